// Round 14
// baseline (136.162 us; speedup 1.0000x reference)
//
#include <hip/hip_runtime.h>
#include <hip/hip_bf16.h>

// Problem constants
#define BATCH 32
#define NTOK 1024          // 32x32
#define CH 256
#define HEADS 8
#define HD 32
#define AGENTS 49
#define WIN 32
#define QKV_N 768
#define SCALE 0.17677669529663687f   // 1/sqrt(32)

typedef unsigned short u16;
typedef __attribute__((ext_vector_type(2))) unsigned short u16x2;
typedef __attribute__((ext_vector_type(8))) unsigned short u16x8;
typedef __attribute__((ext_vector_type(8))) short short8;
typedef __attribute__((ext_vector_type(4))) float f32x4;

__device__ __forceinline__ void gload_lds16(const void* g, const void* l) {
    __builtin_amdgcn_global_load_lds(
        (const __attribute__((address_space(1))) unsigned int*)g,
        (__attribute__((address_space(3))) unsigned int*)l, 16, 0, 0);
}

__device__ __forceinline__ u16 f2bf1(float f) {
    unsigned u = __builtin_bit_cast(unsigned, f);
    u += 0x7fffu + ((u >> 16) & 1u);
    return (u16)(u >> 16);
}
__device__ __forceinline__ float bf2f(u16 v) {
    unsigned u = ((unsigned)v) << 16;
    return __builtin_bit_cast(float, u);
}

// ---------------- fp32 -> bf16 conversion, 8 elems/thread ----------------
__global__ void f2bf_kernel(const float* __restrict__ in, u16* __restrict__ out, int n8) {
    int i = blockIdx.x * 256 + threadIdx.x;
    if (i >= n8) return;
    float4 v0 = ((const float4*)in)[i * 2];
    float4 v1 = ((const float4*)in)[i * 2 + 1];
    u16x8 o;
    o[0] = f2bf1(v0.x); o[1] = f2bf1(v0.y); o[2] = f2bf1(v0.z); o[3] = f2bf1(v0.w);
    o[4] = f2bf1(v1.x); o[5] = f2bf1(v1.y); o[6] = f2bf1(v1.z); o[7] = f2bf1(v1.w);
    ((u16x8*)out)[i] = o;
}

// cls rows (b*1025) of xbf: bf16(x) for the proj GEMM
__global__ void cls_bf16(const float* __restrict__ x, u16* __restrict__ xbf) {
    size_t off = ((size_t)blockIdx.x * 1025) * CH + threadIdx.x;
    xbf[off] = f2bf1(x[off]);
}

// ---------------- bf16 MFMA GEMM: C[M,N] = A[M,K] @ B[N,K]^T (+bias) ----------------
// amode==2: A comes from fp32 x (cls-skip layout), converted in-register during staging.
__global__ __launch_bounds__(256) void gemm_bf16(const u16* __restrict__ A,
                                                 const u16* __restrict__ B,
                                                 float* __restrict__ C,
                                                 u16* __restrict__ C16,
                                                 const float* __restrict__ A32,
                                                 int M, int N, int K,
                                                 const float* __restrict__ bias,
                                                 int amode) {
    __shared__ u16 As[128 * 32];
    __shared__ u16 Bs[128 * 32];
    const int tid = threadIdx.x;
    const int lane = tid & 63;
    const int wid = tid >> 6;
    const int row0 = blockIdx.x * 128, col0 = blockIdx.y * 128;
    const int wr = wid >> 1, wc = wid & 1;
    const int fr = lane & 15, fq = lane >> 4;

    f32x4 acc[4][4];
#pragma unroll
    for (int m = 0; m < 4; ++m)
#pragma unroll
        for (int n = 0; n < 4; ++n) acc[m][n] = (f32x4)(0.f);

    for (int k0 = 0; k0 < K; k0 += 32) {
#pragma unroll
        for (int r = 0; r < 2; ++r) {
            int trow = (tid >> 2) + r * 64;
            int tcol = (tid & 3) * 8;
            int grow = row0 + trow;
            if (amode == 2) {
                // fp32 A with cls-skip; convert in-register, ds_write same tile layout
                int bb = grow >> 10, nn = grow & 1023;
                const float* src = A32 + ((size_t)(bb * 1025 + nn + 1)) * 256 + (size_t)(k0 + tcol);
                float4 v0 = *(const float4*)src;
                float4 v1 = *(const float4*)(src + 4);
                u16x8 o;
                o[0] = f2bf1(v0.x); o[1] = f2bf1(v0.y); o[2] = f2bf1(v0.z); o[3] = f2bf1(v0.w);
                o[4] = f2bf1(v1.x); o[5] = f2bf1(v1.y); o[6] = f2bf1(v1.z); o[7] = f2bf1(v1.w);
                *(u16x8*)&As[trow * 32 + tcol] = o;
            } else {
                size_t aoff;
                int gr = grow;
                if (gr >= M) gr = M - 1;
                aoff = (size_t)gr * K + (size_t)(k0 + tcol);
                gload_lds16(A + aoff, (const char*)As + wid * 1024 + r * 4096);
            }
            int brow = col0 + trow;
            gload_lds16(B + (size_t)brow * K + (size_t)(k0 + tcol),
                        (const char*)Bs + wid * 1024 + r * 4096);
        }
        __syncthreads();

        short8 af[4], bf[4];
#pragma unroll
        for (int m = 0; m < 4; ++m)
            af[m] = *(const short8*)&As[(wr * 64 + m * 16 + fr) * 32 + fq * 8];
#pragma unroll
        for (int n = 0; n < 4; ++n)
            bf[n] = *(const short8*)&Bs[(wc * 64 + n * 16 + fr) * 32 + fq * 8];
        __builtin_amdgcn_s_setprio(1);
#pragma unroll
        for (int m = 0; m < 4; ++m)
#pragma unroll
            for (int n = 0; n < 4; ++n)
                acc[m][n] = __builtin_amdgcn_mfma_f32_16x16x32_bf16(af[m], bf[n], acc[m][n], 0, 0, 0);
        __builtin_amdgcn_s_setprio(0);
        __syncthreads();
    }

#pragma unroll
    for (int m = 0; m < 4; ++m) {
#pragma unroll
        for (int j = 0; j < 4; ++j) {
            int row = row0 + wr * 64 + m * 16 + fq * 4 + j;
            if (row < M) {
#pragma unroll
                for (int n = 0; n < 4; ++n) {
                    int col = col0 + wc * 64 + n * 16 + fr;
                    float v = acc[m][n][j];
                    if (bias) v += bias[col];
                    if (C16) C16[(size_t)row * N + col] = f2bf1(v);
                    else     C[(size_t)row * N + col] = v;
                }
            }
        }
    }
}

// ------- adaptive avg pool of q (bf16) -> agents (b,49,256) f32 -------
__global__ __launch_bounds__(256) void pool_kernel(const u16* __restrict__ qkvb,
                                                   float* __restrict__ agents) {
    int b = blockIdx.x / 7, py = blockIdx.x % 7;
    int ch = threadIdx.x;
    int ys = py * 32 / 7, ye = ((py + 1) * 32 + 6) / 7;
    float acc[7];
#pragma unroll
    for (int i = 0; i < 7; ++i) acc[i] = 0.f;
    for (int y = ys; y < ye; ++y) {
        const u16* rowp = qkvb + ((size_t)(b * NTOK + y * 32)) * QKV_N + ch;
#pragma unroll
        for (int PX = 0; PX < 7; ++PX) {
            const int xs = PX * 32 / 7, xe = ((PX + 1) * 32 + 6) / 7;
            float s = 0.f;
            for (int x = xs; x < xe; ++x) s += bf2f(rowp[(size_t)x * QKV_N]);
            acc[PX] += s;
        }
    }
    int rcnt = ye - ys;
#pragma unroll
    for (int PX = 0; PX < 7; ++PX) {
        const int xs = PX * 32 / 7, xe = ((PX + 1) * 32 + 6) / 7;
        agents[((size_t)(b * AGENTS + py * 7 + PX)) * CH + ch] =
            acc[PX] / (float)(rcnt * (xe - xs));
    }
}

// ---------------- bilinear 7x7 sample (half-pixel, clamped) ----------------
__device__ inline float bilin7(const float* __restrict__ m, float sy, float sx) {
    float fy0 = floorf(sy), fx0 = floorf(sx);
    int y0 = (int)fy0, x0 = (int)fx0;
    float fy = sy - fy0, fx = sx - fx0;
    int y0c = min(max(y0, 0), 6), y1c = min(max(y0 + 1, 0), 6);
    int x0c = min(max(x0, 0), 6), x1c = min(max(x0 + 1, 0), 6);
    float v00 = m[y0c * 7 + x0c], v01 = m[y0c * 7 + x1c];
    float v10 = m[y1c * 7 + x0c], v11 = m[y1c * 7 + x1c];
    return (1.f - fy) * ((1.f - fx) * v00 + fx * v01) + fy * ((1.f - fx) * v10 + fx * v11);
}

// pbn[h][n][64] = resize(an_bias)[h,a,y,x] + ah_bias[h,a,y] + aw_bias[h,a,x]  (n-major, a rows 49..63 zero)
__global__ void pb_kernel(const float* __restrict__ an, const float* __restrict__ ahb,
                          const float* __restrict__ awb, float* __restrict__ pbn) {
    int h = blockIdx.x >> 6, a = blockIdx.x & 63;
    if (a >= AGENTS) {
        for (int n = threadIdx.x; n < NTOK; n += 256)
            pbn[((size_t)(h * NTOK + n)) * 64 + a] = 0.f;
        return;
    }
    const float* m = an + (h * AGENTS + a) * 49;
    for (int n = threadIdx.x; n < NTOK; n += 256) {
        int y = n >> 5, x = n & 31;
        float v = bilin7(m, (y + 0.5f) * (7.f / 32.f) - 0.5f, (x + 0.5f) * (7.f / 32.f) - 0.5f);
        v += ahb[(h * AGENTS + a) * 32 + y] + awb[(h * AGENTS + a) * 32 + x];
        pbn[((size_t)(h * NTOK + n)) * 64 + a] = v;
    }
}

// abT[h][a][n] = resize(na_bias)[h,a,y,x] + ha_bias[h,y,a] + wa_bias[h,x,a]   (a-major)
__global__ void ab_kernel(const float* __restrict__ na, const float* __restrict__ hab,
                          const float* __restrict__ wab, float* __restrict__ abT) {
    int idx = blockIdx.x * 256 + threadIdx.x;          // = (h*49 + a)*1024 + n
    if (idx >= HEADS * AGENTS * NTOK) return;
    int h = idx / (AGENTS * NTOK);
    int r = idx % (AGENTS * NTOK);
    int a = r / NTOK, n = r % NTOK;
    int y = n >> 5, x = n & 31;
    const float* m = na + (h * AGENTS + a) * 49;
    float v = bilin7(m, (y + 0.5f) * (7.f / 32.f) - 0.5f, (x + 0.5f) * (7.f / 32.f) - 0.5f);
    v += hab[(h * 32 + y) * AGENTS + a] + wab[(h * 32 + x) * AGENTS + a];
    abT[idx] = v;
}

// ============ fused attention: agent-attn (MFMA) + q-attn (MFMA) + dwc ============
// grid = 256 (b,h); 512 threads = 8 waves. Phase 1 = agent attention -> avT in LDS.
// Phase 2 = q attention + depthwise conv; V taps and PV B-operand from the Vt transpose.
// VTP=1038: row stride 519 dw, 519%32=7 -> d-rows land on distinct banks.
// OSTR=36: O-write 2-way (free); merge read d-fastest (conflict-free).
#define VTP 1038
#define OSTR 36
__global__ __launch_bounds__(512) void fused_attn(const u16* __restrict__ qkvb,
                                                  const float* __restrict__ agents,
                                                  const float* __restrict__ pbn,
                                                  const float* __restrict__ abT,
                                                  const float* __restrict__ dwc_w,
                                                  const float* __restrict__ dwc_b,
                                                  u16* __restrict__ outbf) {
    int b = blockIdx.x >> 3, h = blockIdx.x & 7;
    int tid = threadIdx.x, lane = tid & 63, w = tid >> 6;
    const int fr = lane & 15, fq = lane >> 4;

    __shared__ u16 ah_lds[64 * 32];       // 4 KB, scale folded, rows 49..63 zero
    __shared__ u16 Vt[32 * VTP];          // 66.4 KB  V^T [dim][token] (both phases)
    __shared__ float PO[8][2304];         // 73.7 KB  per-wave P/O scratch (O: 64 x OSTR=36)
    __shared__ float lsum_lds[8][64];     // 2 KB
    __shared__ u16 avT[32][72];           // 4.6 KB  agent_v^T bf16 (phase 2)
    __shared__ float w9[9][32];           // 1.15 KB
    __shared__ float bia[32];

    u16*   Pw = (u16*)&PO[w][0];
    float* Ow = &PO[w][0];

    // ---- staging (cooperative) ----
    for (int li = tid; li < 64 * 32; li += 512) {
        int a = li >> 5, d = li & 31;
        float v = (a < AGENTS) ? agents[((size_t)(b * AGENTS + a)) * CH + h * HD + d] * SCALE : 0.f;
        ah_lds[li] = f2bf1(v);
    }
    // V^T staging: token-pair repack -> u16x2 writes (<=2-way banked)
    for (int li = tid; li < 512 * 4; li += 512) {
        int p = li >> 2, d8 = (li & 3) * 8;       // tokens 2p,2p+1 ; dims d8..d8+7
        const u16* g0 = &qkvb[((size_t)(b * NTOK + 2 * p)) * QKV_N + 2 * CH + h * HD + d8];
        u16x8 va = *(const u16x8*)g0;
        u16x8 vb = *(const u16x8*)(g0 + QKV_N);
#pragma unroll
        for (int j = 0; j < 8; ++j) {
            u16x2 w2; w2[0] = va[j]; w2[1] = vb[j];
            *(u16x2*)&Vt[(d8 + j) * VTP + 2 * p] = w2;
        }
    }
    for (int li = tid; li < 288; li += 512) {
        int t = li >> 5, d = li & 31;
        w9[t][d] = dwc_w[(h * HD + d) * 9 + t];
    }
    if (tid < 32) bia[tid] = dwc_b[h * HD + tid];
    __syncthreads();

    // ================= phase 1: agent attention =================
    short8 ahf[4];
#pragma unroll
    for (int mt = 0; mt < 4; ++mt)
        ahf[mt] = *(const short8*)&ah_lds[(mt * 16 + fr) * 32 + fq * 8];

    // preload K fragments for BOTH chunks
    short8 kf[2][4];
#pragma unroll
    for (int c2 = 0; c2 < 2; ++c2)
#pragma unroll
        for (int nt = 0; nt < 4; ++nt)
            kf[c2][nt] = *(const short8*)&qkvb[((size_t)(b * NTOK + w * 128 + c2 * 64 + nt * 16 + fr)) * QKV_N + CH + h * HD + fq * 8];

    float lsum[4][4];
#pragma unroll
    for (int mt = 0; mt < 4; ++mt)
#pragma unroll
        for (int j = 0; j < 4; ++j) lsum[mt][j] = 0.f;
    f32x4 accA[4][2];
#pragma unroll
    for (int mt = 0; mt < 4; ++mt)
#pragma unroll
        for (int ntd = 0; ntd < 2; ++ntd) accA[mt][ntd] = (f32x4)(0.f);

    const float* pbnh = pbn + (size_t)h * NTOK * 64;

#pragma unroll
    for (int c2 = 0; c2 < 2; ++c2) {
        int tb = w * 128 + c2 * 64;

        f32x4 pbq[2][4];
#pragma unroll
        for (int nt = 0; nt < 4; ++nt)
            pbq[0][nt] = *(const f32x4*)&pbnh[(size_t)(tb + nt * 16 + fr) * 64 + fq * 4];

#pragma unroll
        for (int mt = 0; mt < 4; ++mt) {
            f32x4 accS[4];
            __builtin_amdgcn_s_setprio(1);
#pragma unroll
            for (int nt = 0; nt < 4; ++nt)
                accS[nt] = __builtin_amdgcn_mfma_f32_16x16x32_bf16(ahf[mt], kf[c2][nt], (f32x4)(0.f), 0, 0, 0);
            __builtin_amdgcn_s_setprio(0);
            if (mt < 3) {
#pragma unroll
                for (int nt = 0; nt < 4; ++nt)
                    pbq[(mt + 1) & 1][nt] = *(const f32x4*)&pbnh[(size_t)(tb + nt * 16 + fr) * 64 + (mt + 1) * 16 + fq * 4];
            }
#pragma unroll
            for (int j = 0; j < 4; ++j) {
                int a = mt * 16 + fq * 4 + j;
#pragma unroll
                for (int nt = 0; nt < 4; ++nt) {
                    float e = __expf(accS[nt][j] + pbq[mt & 1][nt][j]);
                    lsum[mt][j] += e;
                    Pw[a * 72 + nt * 16 + fr] = f2bf1(e);
                }
            }
        }

        short8 pf[4][2], vf[2][2];
#pragma unroll
        for (int mt = 0; mt < 4; ++mt)
#pragma unroll
            for (int kc = 0; kc < 2; ++kc)
                pf[mt][kc] = *(const short8*)&Pw[(mt * 16 + fr) * 72 + kc * 32 + fq * 8];
#pragma unroll
        for (int ntd = 0; ntd < 2; ++ntd)
#pragma unroll
            for (int kc = 0; kc < 2; ++kc)
                vf[ntd][kc] = *(const short8*)&Vt[(ntd * 16 + fr) * VTP + tb + kc * 32 + fq * 8];

        __builtin_amdgcn_s_setprio(1);
#pragma unroll
        for (int mt = 0; mt < 4; ++mt)
#pragma unroll
            for (int kc = 0; kc < 2; ++kc)
#pragma unroll
                for (int ntd = 0; ntd < 2; ++ntd)
                    accA[mt][ntd] = __builtin_amdgcn_mfma_f32_16x16x32_bf16(pf[mt][kc], vf[ntd][kc], accA[mt][ntd], 0, 0, 0);
        __builtin_amdgcn_s_setprio(0);
    }

#pragma unroll
    for (int mt = 0; mt < 4; ++mt)
#pragma unroll
        for (int j = 0; j < 4; ++j) {
            float s = lsum[mt][j];
            s += __shfl_xor(s, 1);
            s += __shfl_xor(s, 2);
            s += __shfl_xor(s, 4);
            s += __shfl_xor(s, 8);
            lsum[mt][j] = s;
        }
    if (fr == 0) {
#pragma unroll
        for (int mt = 0; mt < 4; ++mt)
#pragma unroll
            for (int j = 0; j < 4; ++j)
                lsum_lds[w][mt * 16 + fq * 4 + j] = lsum[mt][j];
    }

    // TBAA guard: float stores below alias the u16 P reads above (type-punned region)
    asm volatile("s_waitcnt lgkmcnt(0)" ::: "memory");
    __builtin_amdgcn_sched_barrier(0);

#pragma unroll
    for (int mt = 0; mt < 4; ++mt)
#pragma unroll
        for (int ntd = 0; ntd < 2; ++ntd)
#pragma unroll
            for (int j = 0; j < 4; ++j)
                Ow[(mt * 16 + fq * 4 + j) * OSTR + ntd * 16 + fr] = accA[mt][ntd][j];

    __syncthreads();

    // merge 8 waves -> avT. d fastest -> each 32-lane group sweeps 32 banks (conflict-free).
    for (int li = tid; li < 64 * HD; li += 512) {
        int d = li & 31, a = li >> 5;
        float val = 0.f;
        if (a < AGENTS) {
            float L = 0.f, o = 0.f;
#pragma unroll
            for (int ww = 0; ww < 8; ++ww) {
                o += PO[ww][a * OSTR + d];
                L += lsum_lds[ww][a];
            }
            val = o / L;
        }
        avT[d][a] = f2bf1(val);
    }
    __syncthreads();

    // ================= phase 2: q attention + dwc =================
    short8 avf[2][2];
#pragma unroll
    for (int ntd = 0; ntd < 2; ++ntd)
#pragma unroll
        for (int kc = 0; kc < 2; ++kc)
            avf[ntd][kc] = *(const short8*)&avT[ntd * 16 + fr][kc * 32 + fq * 8];

    // preload ALL Q fragments
    short8 qf2[4][2];
#pragma unroll
    for (int hh = 0; hh < 4; ++hh)
#pragma unroll
        for (int mt2 = 0; mt2 < 2; ++mt2)
            qf2[hh][mt2] = *(const short8*)(qkvb + ((size_t)(b * NTOK + w * 128 + hh * 32 + mt2 * 16 + fr)) * QKV_N + h * HD + fq * 8);

    const float* abTh = abT + (size_t)h * AGENTS * NTOK;

#pragma unroll
    for (int hh = 0; hh < 4; ++hh) {
        int hb = w * 128 + hh * 32;

        f32x4 abv[2][4];
#pragma unroll
        for (int mt2 = 0; mt2 < 2; ++mt2)
#pragma unroll
            for (int nt = 0; nt < 4; ++nt)
                abv[mt2][nt] = *(const f32x4*)&abTh[(size_t)min(nt * 16 + fr, AGENTS - 1) * NTOK + hb + mt2 * 16 + fq * 4];

#pragma unroll
        for (int mt2 = 0; mt2 < 2; ++mt2) {
            f32x4 accS[4];
            __builtin_amdgcn_s_setprio(1);
#pragma unroll
            for (int nt = 0; nt < 4; ++nt)
                accS[nt] = __builtin_amdgcn_mfma_f32_16x16x32_bf16(qf2[hh][mt2], ahf[nt], (f32x4)(0.f), 0, 0, 0);
            __builtin_amdgcn_s_setprio(0);

            float e[4][4];   // [j][nt]
            float ps[4];
#pragma unroll
            for (int j = 0; j < 4; ++j) ps[j] = 0.f;
#pragma unroll
            for (int j = 0; j < 4; ++j) {
#pragma unroll
                for (int nt = 0; nt < 4; ++nt) {
                    int a = nt * 16 + fr;
                    float s = accS[nt][j] + abv[mt2][nt][j];
                    float ev = (a < AGENTS) ? __expf(s) : 0.f;
                    e[j][nt] = ev;
                    ps[j] += ev;
                }
            }
#pragma unroll
            for (int j = 0; j < 4; ++j) {
                ps[j] += __shfl_xor(ps[j], 1);
                ps[j] += __shfl_xor(ps[j], 2);
                ps[j] += __shfl_xor(ps[j], 4);
                ps[j] += __shfl_xor(ps[j], 8);
            }
#pragma unroll
            for (int j = 0; j < 4; ++j) {
                float inv = 1.f / ps[j];
                int tl = mt2 * 16 + fq * 4 + j;
#pragma unroll
                for (int nt = 0; nt < 4; ++nt)
                    Pw[tl * 68 + nt * 16 + fr] = f2bf1(e[j][nt] * inv);
            }
        }

        short8 pf2[2][2];
#pragma unroll
        for (int mt2 = 0; mt2 < 2; ++mt2)
#pragma unroll
            for (int kc = 0; kc < 2; ++kc)
                pf2[mt2][kc] = *(const short8*)&Pw[(mt2 * 16 + fr) * 68 + kc * 32 + fq * 8];

        f32x4 accO[2][2];
#pragma unroll
        for (int mt2 = 0; mt2 < 2; ++mt2)
#pragma unroll
            for (int ntd = 0; ntd < 2; ++ntd) accO[mt2][ntd] = (f32x4)(0.f);
        __builtin_amdgcn_s_setprio(1);
#pragma unroll
        for (int mt2 = 0; mt2 < 2; ++mt2)
#pragma unroll
            for (int kc = 0; kc < 2; ++kc)
#pragma unroll
                for (int ntd = 0; ntd < 2; ++ntd)
                    accO[mt2][ntd] = __builtin_amdgcn_mfma_f32_16x16x32_bf16(pf2[mt2][kc], avf[ntd][kc], accO[mt2][ntd], 0, 0, 0);
        __builtin_amdgcn_s_setprio(0);

        // fused dwc + bias + bf16 store (C-layout epilogue); V taps via u16x2 spans
        int y = w * 4 + hh;
#pragma unroll
        for (int ntd = 0; ntd < 2; ++ntd) {
            int d = ntd * 16 + fr;
            float wv[9];
#pragma unroll
            for (int t = 0; t < 9; ++t) wv[t] = w9[t][d];
            float bv = bia[d];
            const u16* Vd = &Vt[d * VTP];
#pragma unroll
            for (int mt2 = 0; mt2 < 2; ++mt2) {
                int x0 = mt2 * 16 + fq * 4;
                float sp[3][8];      // tokens x0-2 .. x0+5 per dy row
#pragma unroll
                for (int dy = 0; dy < 3; ++dy) {
                    int yy = y - 1 + dy;
                    if (yy >= 0 && yy < 32) {
                        int base = yy * 32 + x0 - 2;     // even -> 4B-aligned
                        u16x2 r0 = *(const u16x2*)&Vd[base];
                        u16x2 r1 = *(const u16x2*)&Vd[base + 2];
                        u16x2 r2 = *(const u16x2*)&Vd[base + 4];
                        u16x2 r3 = *(const u16x2*)&Vd[base + 6];
                        sp[dy][0] = bf2f(r0[0]); sp[dy][1] = bf2f(r0[1]);
                        sp[dy][2] = bf2f(r1[0]); sp[dy][3] = bf2f(r1[1]);
                        sp[dy][4] = bf2f(r2[0]); sp[dy][5] = bf2f(r2[1]);
                        sp[dy][6] = bf2f(r3[0]); sp[dy][7] = bf2f(r3[1]);
                    } else {
#pragma unroll
                        for (int k = 0; k < 8; ++k) sp[dy][k] = 0.f;
                    }
                }
                float vv[3][6];      // xx = x0-1+k, masked at image edges
#pragma unroll
                for (int dy = 0; dy < 3; ++dy)
#pragma unroll
                    for (int k = 0; k < 6; ++k) {
                        int xx = x0 - 1 + k;
                        vv[dy][k] = (xx >= 0 && xx < 32) ? sp[dy][k + 1] : 0.f;
                    }
#pragma unroll
                for (int j = 0; j < 4; ++j) {
                    float o = accO[mt2][ntd][j] + bv;
#pragma unroll
                    for (int dy = 0; dy < 3; ++dy)
#pragma unroll
                        for (int dx = 0; dx < 3; ++dx)
                            o = fmaf(wv[dy * 3 + dx], vv[dy][j + dx], o);
                    int n = y * 32 + x0 + j;
                    outbf[((size_t)(b * 1025 + 1 + n)) * CH + h * HD + d] = f2bf1(o);
                }
            }
        }
    }
}
#undef VTP
#undef OSTR

extern "C" void kernel_launch(void* const* d_in, const int* in_sizes, int n_in,
                              void* d_out, int out_size, void* d_ws, size_t ws_size,
                              hipStream_t stream) {
    const float* x      = (const float*)d_in[0];
    const float* qkv_w  = (const float*)d_in[1];
    const float* proj_w = (const float*)d_in[2];
    const float* proj_b = (const float*)d_in[3];
    const float* dwc_w  = (const float*)d_in[4];
    const float* dwc_b  = (const float*)d_in[5];
    const float* an_b   = (const float*)d_in[6];
    const float* ah_b   = (const float*)d_in[7];
    const float* aw_b   = (const float*)d_in[8];
    const float* na_b   = (const float*)d_in[9];
    const float* ha_b   = (const float*)d_in[10];
    const float* wa_b   = (const float*)d_in[11];
    float* out = (float*)d_out;

    float* ws      = (float*)d_ws;
    u16*   qkvb    = (u16*)ws;                 // 25,165,824 u16 (bf16 qkv)
    float* agents  = ws + 12582912;            // 401,408 f
    float* pbn     = agents + 401408;          // 524,288 f  (n-major [h][n][64])
    float* abT     = pbn + 524288;             // 401,408 f  (a-major [h][a][n])
    u16* xbf  = (u16*)(abT + 401408);          // 8,396,800 u16 (cls bf16 + fused bf16 rows)
    u16* qwbf = xbf + 8396800;                 // 196,608 u16
    u16* pwbf = qwbf + 196608;                 // 65,536 u16

    // weight conversions + cls rows (x itself is consumed fp32 by the qkv GEMM)
    f2bf_kernel<<<96, 256, 0, stream>>>(qkv_w, qwbf, 196608 / 8);
    f2bf_kernel<<<32, 256, 0, stream>>>(proj_w, pwbf, 65536 / 8);
    cls_bf16<<<BATCH, 256, 0, stream>>>(x, xbf);
    // 1. qkv(bf16) = xs @ qkv_w^T   (M=32768, N=768, K=256); A read fp32 + converted in-kernel
    gemm_bf16<<<dim3(256, 6), 256, 0, stream>>>(nullptr, qwbf, nullptr, qkvb, x, 32768, 768, 256, nullptr, 2);
    // 2. agent pooling of q
    pool_kernel<<<BATCH * 7, 256, 0, stream>>>(qkvb, agents);
    // 3. position biases (pbn n-major with zero pad rows; abT a-major)
    pb_kernel<<<HEADS * 64, 256, 0, stream>>>(an_b, ah_b, aw_b, pbn);
    ab_kernel<<<(HEADS * AGENTS * NTOK + 255) / 256, 256, 0, stream>>>(na_b, ha_b, wa_b, abT);
    // 4. fused agent-attn + q-attn + dwc -> bf16 rows 1..1024 of xbf
    fused_attn<<<BATCH * HEADS, 512, 0, stream>>>(qkvb, agents, pbn, abT, dwc_w, dwc_b, xbf);
    // 5. out = fused @ proj_w^T + proj_b  (M=32800, N=256, K=256)
    gemm_bf16<<<dim3(257, 2), 256, 0, stream>>>(xbf, pwbf, out, nullptr, nullptr, 32800, 256, 256, proj_b, 0);
}

// Round 15
// 135.592 us; speedup vs baseline: 1.0042x; 1.0042x over previous
//
#include <hip/hip_runtime.h>
#include <hip/hip_bf16.h>

// Problem constants
#define BATCH 32
#define NTOK 1024          // 32x32
#define CH 256
#define HEADS 8
#define HD 32
#define AGENTS 49
#define WIN 32
#define QKV_N 768
#define SCALE 0.17677669529663687f   // 1/sqrt(32)

typedef unsigned short u16;
typedef __attribute__((ext_vector_type(2))) unsigned short u16x2;
typedef __attribute__((ext_vector_type(8))) unsigned short u16x8;
typedef __attribute__((ext_vector_type(8))) short short8;
typedef __attribute__((ext_vector_type(4))) float f32x4;

__device__ __forceinline__ void gload_lds16(const void* g, const void* l) {
    __builtin_amdgcn_global_load_lds(
        (const __attribute__((address_space(1))) unsigned int*)g,
        (__attribute__((address_space(3))) unsigned int*)l, 16, 0, 0);
}

__device__ __forceinline__ u16 f2bf1(float f) {
    unsigned u = __builtin_bit_cast(unsigned, f);
    u += 0x7fffu + ((u >> 16) & 1u);
    return (u16)(u >> 16);
}
__device__ __forceinline__ float bf2f(u16 v) {
    unsigned u = ((unsigned)v) << 16;
    return __builtin_bit_cast(float, u);
}

// ---------------- fp32 -> bf16 conversion, 8 elems/thread ----------------
__global__ void f2bf_kernel(const float* __restrict__ in, u16* __restrict__ out, int n8) {
    int i = blockIdx.x * 256 + threadIdx.x;
    if (i >= n8) return;
    float4 v0 = ((const float4*)in)[i * 2];
    float4 v1 = ((const float4*)in)[i * 2 + 1];
    u16x8 o;
    o[0] = f2bf1(v0.x); o[1] = f2bf1(v0.y); o[2] = f2bf1(v0.z); o[3] = f2bf1(v0.w);
    o[4] = f2bf1(v1.x); o[5] = f2bf1(v1.y); o[6] = f2bf1(v1.z); o[7] = f2bf1(v1.w);
    ((u16x8*)out)[i] = o;
}

// ---------------- bf16 MFMA GEMM: C[M,N] = A[M,K] @ B[N,K]^T (+bias) ----------------
__global__ __launch_bounds__(256) void gemm_bf16(const u16* __restrict__ A,
                                                 const u16* __restrict__ B,
                                                 float* __restrict__ C,
                                                 u16* __restrict__ C16,
                                                 int M, int N, int K,
                                                 const float* __restrict__ bias,
                                                 int amode) {
    __shared__ u16 As[128 * 32];
    __shared__ u16 Bs[128 * 32];
    const int tid = threadIdx.x;
    const int lane = tid & 63;
    const int wid = tid >> 6;
    const int row0 = blockIdx.x * 128, col0 = blockIdx.y * 128;
    const int wr = wid >> 1, wc = wid & 1;
    const int fr = lane & 15, fq = lane >> 4;

    f32x4 acc[4][4];
#pragma unroll
    for (int m = 0; m < 4; ++m)
#pragma unroll
        for (int n = 0; n < 4; ++n) acc[m][n] = (f32x4)(0.f);

    for (int k0 = 0; k0 < K; k0 += 32) {
#pragma unroll
        for (int r = 0; r < 2; ++r) {
            int trow = (tid >> 2) + r * 64;
            int tcol = (tid & 3) * 8;
            size_t aoff;
            int grow = row0 + trow;
            if (amode == 1) {
                int bb = grow >> 10, nn = grow & 1023;
                aoff = ((size_t)(bb * 1025 + nn + 1)) * 256 + (size_t)(k0 + tcol);
            } else {
                if (grow >= M) grow = M - 1;
                aoff = (size_t)grow * K + (size_t)(k0 + tcol);
            }
            gload_lds16(A + aoff, (const char*)As + wid * 1024 + r * 4096);
            int brow = col0 + trow;
            gload_lds16(B + (size_t)brow * K + (size_t)(k0 + tcol),
                        (const char*)Bs + wid * 1024 + r * 4096);
        }
        __syncthreads();

        short8 af[4], bf[4];
#pragma unroll
        for (int m = 0; m < 4; ++m)
            af[m] = *(const short8*)&As[(wr * 64 + m * 16 + fr) * 32 + fq * 8];
#pragma unroll
        for (int n = 0; n < 4; ++n)
            bf[n] = *(const short8*)&Bs[(wc * 64 + n * 16 + fr) * 32 + fq * 8];
#pragma unroll
        for (int m = 0; m < 4; ++m)
#pragma unroll
            for (int n = 0; n < 4; ++n)
                acc[m][n] = __builtin_amdgcn_mfma_f32_16x16x32_bf16(af[m], bf[n], acc[m][n], 0, 0, 0);
        __syncthreads();
    }

#pragma unroll
    for (int m = 0; m < 4; ++m) {
#pragma unroll
        for (int j = 0; j < 4; ++j) {
            int row = row0 + wr * 64 + m * 16 + fq * 4 + j;
            if (row < M) {
#pragma unroll
                for (int n = 0; n < 4; ++n) {
                    int col = col0 + wc * 64 + n * 16 + fr;
                    float v = acc[m][n][j];
                    if (bias) v += bias[col];
                    if (C16) C16[(size_t)row * N + col] = f2bf1(v);
                    else     C[(size_t)row * N + col] = v;
                }
            }
        }
    }
}

// ------- adaptive avg pool of q (bf16) -> agents (b,49,256) f32 -------
__global__ __launch_bounds__(256) void pool_kernel(const u16* __restrict__ qkvb,
                                                   float* __restrict__ agents) {
    int b = blockIdx.x / 7, py = blockIdx.x % 7;
    int ch = threadIdx.x;
    int ys = py * 32 / 7, ye = ((py + 1) * 32 + 6) / 7;
    float acc[7];
#pragma unroll
    for (int i = 0; i < 7; ++i) acc[i] = 0.f;
    for (int y = ys; y < ye; ++y) {
        const u16* rowp = qkvb + ((size_t)(b * NTOK + y * 32)) * QKV_N + ch;
#pragma unroll
        for (int PX = 0; PX < 7; ++PX) {
            const int xs = PX * 32 / 7, xe = ((PX + 1) * 32 + 6) / 7;
            float s = 0.f;
            for (int x = xs; x < xe; ++x) s += bf2f(rowp[(size_t)x * QKV_N]);
            acc[PX] += s;
        }
    }
    int rcnt = ye - ys;
#pragma unroll
    for (int PX = 0; PX < 7; ++PX) {
        const int xs = PX * 32 / 7, xe = ((PX + 1) * 32 + 6) / 7;
        agents[((size_t)(b * AGENTS + py * 7 + PX)) * CH + ch] =
            acc[PX] / (float)(rcnt * (xe - xs));
    }
}

// ---------------- bilinear 7x7 sample (half-pixel, clamped) ----------------
__device__ inline float bilin7(const float* __restrict__ m, float sy, float sx) {
    float fy0 = floorf(sy), fx0 = floorf(sx);
    int y0 = (int)fy0, x0 = (int)fx0;
    float fy = sy - fy0, fx = sx - fx0;
    int y0c = min(max(y0, 0), 6), y1c = min(max(y0 + 1, 0), 6);
    int x0c = min(max(x0, 0), 6), x1c = min(max(x0 + 1, 0), 6);
    float v00 = m[y0c * 7 + x0c], v01 = m[y0c * 7 + x1c];
    float v10 = m[y1c * 7 + x0c], v11 = m[y1c * 7 + x1c];
    return (1.f - fy) * ((1.f - fx) * v00 + fx * v01) + fy * ((1.f - fx) * v10 + fx * v11);
}

// pbn[h][n][64] = resize(an_bias)[h,a,y,x] + ah_bias[h,a,y] + aw_bias[h,a,x]  (n-major, a rows 49..63 zero)
__global__ void pb_kernel(const float* __restrict__ an, const float* __restrict__ ahb,
                          const float* __restrict__ awb, float* __restrict__ pbn) {
    int h = blockIdx.x >> 6, a = blockIdx.x & 63;
    if (a >= AGENTS) {
        for (int n = threadIdx.x; n < NTOK; n += 256)
            pbn[((size_t)(h * NTOK + n)) * 64 + a] = 0.f;
        return;
    }
    const float* m = an + (h * AGENTS + a) * 49;
    for (int n = threadIdx.x; n < NTOK; n += 256) {
        int y = n >> 5, x = n & 31;
        float v = bilin7(m, (y + 0.5f) * (7.f / 32.f) - 0.5f, (x + 0.5f) * (7.f / 32.f) - 0.5f);
        v += ahb[(h * AGENTS + a) * 32 + y] + awb[(h * AGENTS + a) * 32 + x];
        pbn[((size_t)(h * NTOK + n)) * 64 + a] = v;
    }
}

// abT[h][a][n] = resize(na_bias)[h,a,y,x] + ha_bias[h,y,a] + wa_bias[h,x,a]   (a-major)
__global__ void ab_kernel(const float* __restrict__ na, const float* __restrict__ hab,
                          const float* __restrict__ wab, float* __restrict__ abT) {
    int idx = blockIdx.x * 256 + threadIdx.x;          // = (h*49 + a)*1024 + n
    if (idx >= HEADS * AGENTS * NTOK) return;
    int h = idx / (AGENTS * NTOK);
    int r = idx % (AGENTS * NTOK);
    int a = r / NTOK, n = r % NTOK;
    int y = n >> 5, x = n & 31;
    const float* m = na + (h * AGENTS + a) * 49;
    float v = bilin7(m, (y + 0.5f) * (7.f / 32.f) - 0.5f, (x + 0.5f) * (7.f / 32.f) - 0.5f);
    v += hab[(h * 32 + y) * AGENTS + a] + wab[(h * 32 + x) * AGENTS + a];
    abT[idx] = v;
}

// ============ fused attention: agent-attn (MFMA) + q-attn (MFMA) + dwc ============
// grid = 256 (b,h); 512 threads = 8 waves. Phase 1 = agent attention -> avT in LDS.
// Phase 2 = q attention + depthwise conv; V taps and PV B-operand from the Vt transpose.
// VTP=1038: row stride 519 dw, 519%32=7 -> d-rows land on distinct banks.
// OSTR=36: O-write 2-way (free); merge read d-fastest (conflict-free).
// T5: setprio(1) around MFMA clusters (8-wave phase-split kernel -> waves at different
// phases; scheduler favors MFMA-issuing waves. Catalog: +4-7% attn, null on lockstep GEMM).
#define VTP 1038
#define OSTR 36
__global__ __launch_bounds__(512) void fused_attn(const u16* __restrict__ qkvb,
                                                  const float* __restrict__ agents,
                                                  const float* __restrict__ pbn,
                                                  const float* __restrict__ abT,
                                                  const float* __restrict__ dwc_w,
                                                  const float* __restrict__ dwc_b,
                                                  u16* __restrict__ outbf) {
    int b = blockIdx.x >> 3, h = blockIdx.x & 7;
    int tid = threadIdx.x, lane = tid & 63, w = tid >> 6;
    const int fr = lane & 15, fq = lane >> 4;

    __shared__ u16 ah_lds[64 * 32];       // 4 KB, scale folded, rows 49..63 zero
    __shared__ u16 Vt[32 * VTP];          // 66.4 KB  V^T [dim][token] (both phases)
    __shared__ float PO[8][2304];         // 73.7 KB  per-wave P/O scratch (O: 64 x OSTR=36)
    __shared__ float lsum_lds[8][64];     // 2 KB
    __shared__ u16 avT[32][72];           // 4.6 KB  agent_v^T bf16 (phase 2)
    __shared__ float w9[9][32];           // 1.15 KB
    __shared__ float bia[32];

    u16*   Pw = (u16*)&PO[w][0];
    float* Ow = &PO[w][0];

    // ---- staging (cooperative) ----
    for (int li = tid; li < 64 * 32; li += 512) {
        int a = li >> 5, d = li & 31;
        float v = (a < AGENTS) ? agents[((size_t)(b * AGENTS + a)) * CH + h * HD + d] * SCALE : 0.f;
        ah_lds[li] = f2bf1(v);
    }
    // V^T staging: token-pair repack -> u16x2 writes (<=2-way banked)
    for (int li = tid; li < 512 * 4; li += 512) {
        int p = li >> 2, d8 = (li & 3) * 8;       // tokens 2p,2p+1 ; dims d8..d8+7
        const u16* g0 = &qkvb[((size_t)(b * NTOK + 2 * p)) * QKV_N + 2 * CH + h * HD + d8];
        u16x8 va = *(const u16x8*)g0;
        u16x8 vb = *(const u16x8*)(g0 + QKV_N);
#pragma unroll
        for (int j = 0; j < 8; ++j) {
            u16x2 w2; w2[0] = va[j]; w2[1] = vb[j];
            *(u16x2*)&Vt[(d8 + j) * VTP + 2 * p] = w2;
        }
    }
    for (int li = tid; li < 288; li += 512) {
        int t = li >> 5, d = li & 31;
        w9[t][d] = dwc_w[(h * HD + d) * 9 + t];
    }
    if (tid < 32) bia[tid] = dwc_b[h * HD + tid];
    __syncthreads();

    // ================= phase 1: agent attention =================
    short8 ahf[4];
#pragma unroll
    for (int mt = 0; mt < 4; ++mt)
        ahf[mt] = *(const short8*)&ah_lds[(mt * 16 + fr) * 32 + fq * 8];

    // preload K fragments for BOTH chunks
    short8 kf[2][4];
#pragma unroll
    for (int c2 = 0; c2 < 2; ++c2)
#pragma unroll
        for (int nt = 0; nt < 4; ++nt)
            kf[c2][nt] = *(const short8*)&qkvb[((size_t)(b * NTOK + w * 128 + c2 * 64 + nt * 16 + fr)) * QKV_N + CH + h * HD + fq * 8];

    float lsum[4][4];
#pragma unroll
    for (int mt = 0; mt < 4; ++mt)
#pragma unroll
        for (int j = 0; j < 4; ++j) lsum[mt][j] = 0.f;
    f32x4 accA[4][2];
#pragma unroll
    for (int mt = 0; mt < 4; ++mt)
#pragma unroll
        for (int ntd = 0; ntd < 2; ++ntd) accA[mt][ntd] = (f32x4)(0.f);

    const float* pbnh = pbn + (size_t)h * NTOK * 64;

#pragma unroll
    for (int c2 = 0; c2 < 2; ++c2) {
        int tb = w * 128 + c2 * 64;

        f32x4 pbq[2][4];
#pragma unroll
        for (int nt = 0; nt < 4; ++nt)
            pbq[0][nt] = *(const f32x4*)&pbnh[(size_t)(tb + nt * 16 + fr) * 64 + fq * 4];

#pragma unroll
        for (int mt = 0; mt < 4; ++mt) {
            f32x4 accS[4];
            __builtin_amdgcn_s_setprio(1);
#pragma unroll
            for (int nt = 0; nt < 4; ++nt)
                accS[nt] = __builtin_amdgcn_mfma_f32_16x16x32_bf16(ahf[mt], kf[c2][nt], (f32x4)(0.f), 0, 0, 0);
            __builtin_amdgcn_s_setprio(0);
            if (mt < 3) {
#pragma unroll
                for (int nt = 0; nt < 4; ++nt)
                    pbq[(mt + 1) & 1][nt] = *(const f32x4*)&pbnh[(size_t)(tb + nt * 16 + fr) * 64 + (mt + 1) * 16 + fq * 4];
            }
#pragma unroll
            for (int j = 0; j < 4; ++j) {
                int a = mt * 16 + fq * 4 + j;
#pragma unroll
                for (int nt = 0; nt < 4; ++nt) {
                    float e = __expf(accS[nt][j] + pbq[mt & 1][nt][j]);
                    lsum[mt][j] += e;
                    Pw[a * 72 + nt * 16 + fr] = f2bf1(e);
                }
            }
        }

        short8 pf[4][2], vf[2][2];
#pragma unroll
        for (int mt = 0; mt < 4; ++mt)
#pragma unroll
            for (int kc = 0; kc < 2; ++kc)
                pf[mt][kc] = *(const short8*)&Pw[(mt * 16 + fr) * 72 + kc * 32 + fq * 8];
#pragma unroll
        for (int ntd = 0; ntd < 2; ++ntd)
#pragma unroll
            for (int kc = 0; kc < 2; ++kc)
                vf[ntd][kc] = *(const short8*)&Vt[(ntd * 16 + fr) * VTP + tb + kc * 32 + fq * 8];

        __builtin_amdgcn_s_setprio(1);
#pragma unroll
        for (int mt = 0; mt < 4; ++mt)
#pragma unroll
            for (int kc = 0; kc < 2; ++kc)
#pragma unroll
                for (int ntd = 0; ntd < 2; ++ntd)
                    accA[mt][ntd] = __builtin_amdgcn_mfma_f32_16x16x32_bf16(pf[mt][kc], vf[ntd][kc], accA[mt][ntd], 0, 0, 0);
        __builtin_amdgcn_s_setprio(0);
    }

#pragma unroll
    for (int mt = 0; mt < 4; ++mt)
#pragma unroll
        for (int j = 0; j < 4; ++j) {
            float s = lsum[mt][j];
            s += __shfl_xor(s, 1);
            s += __shfl_xor(s, 2);
            s += __shfl_xor(s, 4);
            s += __shfl_xor(s, 8);
            lsum[mt][j] = s;
        }
    if (fr == 0) {
#pragma unroll
        for (int mt = 0; mt < 4; ++mt)
#pragma unroll
            for (int j = 0; j < 4; ++j)
                lsum_lds[w][mt * 16 + fq * 4 + j] = lsum[mt][j];
    }

    // TBAA guard: float stores below alias the u16 P reads above (type-punned region)
    asm volatile("s_waitcnt lgkmcnt(0)" ::: "memory");
    __builtin_amdgcn_sched_barrier(0);

#pragma unroll
    for (int mt = 0; mt < 4; ++mt)
#pragma unroll
        for (int ntd = 0; ntd < 2; ++ntd)
#pragma unroll
            for (int j = 0; j < 4; ++j)
                Ow[(mt * 16 + fq * 4 + j) * OSTR + ntd * 16 + fr] = accA[mt][ntd][j];

    __syncthreads();

    // merge 8 waves -> avT. d fastest -> each 32-lane group sweeps 32 banks (conflict-free).
    for (int li = tid; li < 64 * HD; li += 512) {
        int d = li & 31, a = li >> 5;
        float val = 0.f;
        if (a < AGENTS) {
            float L = 0.f, o = 0.f;
#pragma unroll
            for (int ww = 0; ww < 8; ++ww) {
                o += PO[ww][a * OSTR + d];
                L += lsum_lds[ww][a];
            }
            val = o / L;
        }
        avT[d][a] = f2bf1(val);
    }
    __syncthreads();

    // ================= phase 2: q attention + dwc =================
    short8 avf[2][2];
#pragma unroll
    for (int ntd = 0; ntd < 2; ++ntd)
#pragma unroll
        for (int kc = 0; kc < 2; ++kc)
            avf[ntd][kc] = *(const short8*)&avT[ntd * 16 + fr][kc * 32 + fq * 8];

    // preload ALL Q fragments
    short8 qf2[4][2];
#pragma unroll
    for (int hh = 0; hh < 4; ++hh)
#pragma unroll
        for (int mt2 = 0; mt2 < 2; ++mt2)
            qf2[hh][mt2] = *(const short8*)(qkvb + ((size_t)(b * NTOK + w * 128 + hh * 32 + mt2 * 16 + fr)) * QKV_N + h * HD + fq * 8);

    const float* abTh = abT + (size_t)h * AGENTS * NTOK;

#pragma unroll
    for (int hh = 0; hh < 4; ++hh) {
        int hb = w * 128 + hh * 32;

        f32x4 abv[2][4];
#pragma unroll
        for (int mt2 = 0; mt2 < 2; ++mt2)
#pragma unroll
            for (int nt = 0; nt < 4; ++nt)
                abv[mt2][nt] = *(const f32x4*)&abTh[(size_t)min(nt * 16 + fr, AGENTS - 1) * NTOK + hb + mt2 * 16 + fq * 4];

#pragma unroll
        for (int mt2 = 0; mt2 < 2; ++mt2) {
            f32x4 accS[4];
            __builtin_amdgcn_s_setprio(1);
#pragma unroll
            for (int nt = 0; nt < 4; ++nt)
                accS[nt] = __builtin_amdgcn_mfma_f32_16x16x32_bf16(qf2[hh][mt2], ahf[nt], (f32x4)(0.f), 0, 0, 0);
            __builtin_amdgcn_s_setprio(0);

            float e[4][4];   // [j][nt]
            float ps[4];
#pragma unroll
            for (int j = 0; j < 4; ++j) ps[j] = 0.f;
#pragma unroll
            for (int j = 0; j < 4; ++j) {
#pragma unroll
                for (int nt = 0; nt < 4; ++nt) {
                    int a = nt * 16 + fr;
                    float s = accS[nt][j] + abv[mt2][nt][j];
                    float ev = (a < AGENTS) ? __expf(s) : 0.f;
                    e[j][nt] = ev;
                    ps[j] += ev;
                }
            }
#pragma unroll
            for (int j = 0; j < 4; ++j) {
                ps[j] += __shfl_xor(ps[j], 1);
                ps[j] += __shfl_xor(ps[j], 2);
                ps[j] += __shfl_xor(ps[j], 4);
                ps[j] += __shfl_xor(ps[j], 8);
            }
#pragma unroll
            for (int j = 0; j < 4; ++j) {
                float inv = 1.f / ps[j];
                int tl = mt2 * 16 + fq * 4 + j;
#pragma unroll
                for (int nt = 0; nt < 4; ++nt)
                    Pw[tl * 68 + nt * 16 + fr] = f2bf1(e[j][nt] * inv);
            }
        }

        short8 pf2[2][2];
#pragma unroll
        for (int mt2 = 0; mt2 < 2; ++mt2)
#pragma unroll
            for (int kc = 0; kc < 2; ++kc)
                pf2[mt2][kc] = *(const short8*)&Pw[(mt2 * 16 + fr) * 68 + kc * 32 + fq * 8];

        f32x4 accO[2][2];
#pragma unroll
        for (int mt2 = 0; mt2 < 2; ++mt2)
#pragma unroll
            for (int ntd = 0; ntd < 2; ++ntd) accO[mt2][ntd] = (f32x4)(0.f);
        __builtin_amdgcn_s_setprio(1);
#pragma unroll
        for (int mt2 = 0; mt2 < 2; ++mt2)
#pragma unroll
            for (int kc = 0; kc < 2; ++kc)
#pragma unroll
                for (int ntd = 0; ntd < 2; ++ntd)
                    accO[mt2][ntd] = __builtin_amdgcn_mfma_f32_16x16x32_bf16(pf2[mt2][kc], avf[ntd][kc], accO[mt2][ntd], 0, 0, 0);
        __builtin_amdgcn_s_setprio(0);

        // fused dwc + bias + bf16 store (C-layout epilogue); V taps via u16x2 spans
        int y = w * 4 + hh;
#pragma unroll
        for (int ntd = 0; ntd < 2; ++ntd) {
            int d = ntd * 16 + fr;
            float wv[9];
#pragma unroll
            for (int t = 0; t < 9; ++t) wv[t] = w9[t][d];
            float bv = bia[d];
            const u16* Vd = &Vt[d * VTP];
#pragma unroll
            for (int mt2 = 0; mt2 < 2; ++mt2) {
                int x0 = mt2 * 16 + fq * 4;
                float sp[3][8];      // tokens x0-2 .. x0+5 per dy row
#pragma unroll
                for (int dy = 0; dy < 3; ++dy) {
                    int yy = y - 1 + dy;
                    if (yy >= 0 && yy < 32) {
                        int base = yy * 32 + x0 - 2;     // even -> 4B-aligned
                        u16x2 r0 = *(const u16x2*)&Vd[base];
                        u16x2 r1 = *(const u16x2*)&Vd[base + 2];
                        u16x2 r2 = *(const u16x2*)&Vd[base + 4];
                        u16x2 r3 = *(const u16x2*)&Vd[base + 6];
                        sp[dy][0] = bf2f(r0[0]); sp[dy][1] = bf2f(r0[1]);
                        sp[dy][2] = bf2f(r1[0]); sp[dy][3] = bf2f(r1[1]);
                        sp[dy][4] = bf2f(r2[0]); sp[dy][5] = bf2f(r2[1]);
                        sp[dy][6] = bf2f(r3[0]); sp[dy][7] = bf2f(r3[1]);
                    } else {
#pragma unroll
                        for (int k = 0; k < 8; ++k) sp[dy][k] = 0.f;
                    }
                }
                float vv[3][6];      // xx = x0-1+k, masked at image edges
#pragma unroll
                for (int dy = 0; dy < 3; ++dy)
#pragma unroll
                    for (int k = 0; k < 6; ++k) {
                        int xx = x0 - 1 + k;
                        vv[dy][k] = (xx >= 0 && xx < 32) ? sp[dy][k + 1] : 0.f;
                    }
#pragma unroll
                for (int j = 0; j < 4; ++j) {
                    float o = accO[mt2][ntd][j] + bv;
#pragma unroll
                    for (int dy = 0; dy < 3; ++dy)
#pragma unroll
                        for (int dx = 0; dx < 3; ++dx)
                            o = fmaf(wv[dy * 3 + dx], vv[dy][j + dx], o);
                    int n = y * 32 + x0 + j;
                    outbf[((size_t)(b * 1025 + 1 + n)) * CH + h * HD + d] = f2bf1(o);
                }
            }
        }
    }
}
#undef VTP
#undef OSTR

extern "C" void kernel_launch(void* const* d_in, const int* in_sizes, int n_in,
                              void* d_out, int out_size, void* d_ws, size_t ws_size,
                              hipStream_t stream) {
    const float* x      = (const float*)d_in[0];
    const float* qkv_w  = (const float*)d_in[1];
    const float* proj_w = (const float*)d_in[2];
    const float* proj_b = (const float*)d_in[3];
    const float* dwc_w  = (const float*)d_in[4];
    const float* dwc_b  = (const float*)d_in[5];
    const float* an_b   = (const float*)d_in[6];
    const float* ah_b   = (const float*)d_in[7];
    const float* aw_b   = (const float*)d_in[8];
    const float* na_b   = (const float*)d_in[9];
    const float* ha_b   = (const float*)d_in[10];
    const float* wa_b   = (const float*)d_in[11];
    float* out = (float*)d_out;

    float* ws      = (float*)d_ws;
    u16*   qkvb    = (u16*)ws;                 // 25,165,824 u16 (bf16 qkv)
    float* agents  = ws + 12582912;            // 401,408 f
    float* pbn     = agents + 401408;          // 524,288 f  (n-major [h][n][64])
    float* abT     = pbn + 524288;             // 401,408 f  (a-major [h][a][n])
    u16* xbf  = (u16*)(abT + 401408);          // 8,396,800 u16 (x bf16 -> fused bf16 rows)
    u16* qwbf = xbf + 8396800;                 // 196,608 u16
    u16* pwbf = qwbf + 196608;                 // 65,536 u16

    // conversions (xbf rows b*1025 keep bf16 cls tokens for the proj GEMM;
    // full-x pass also pre-writes every xbf line -> fused_attn's partial-line
    // stores hit resident lines instead of RMW write-allocating, per R14 lesson)
    f2bf_kernel<<<4100, 256, 0, stream>>>(x, xbf, 8396800 / 8);
    f2bf_kernel<<<96, 256, 0, stream>>>(qkv_w, qwbf, 196608 / 8);
    f2bf_kernel<<<32, 256, 0, stream>>>(proj_w, pwbf, 65536 / 8);
    // 1. qkv(bf16) = xs @ qkv_w^T   (M=32768, N=768, K=256)
    gemm_bf16<<<dim3(256, 6), 256, 0, stream>>>(xbf, qwbf, nullptr, qkvb, 32768, 768, 256, nullptr, 1);
    // 2. agent pooling of q
    pool_kernel<<<BATCH * 7, 256, 0, stream>>>(qkvb, agents);
    // 3. position biases (pbn n-major with zero pad rows; abT a-major)
    pb_kernel<<<HEADS * 64, 256, 0, stream>>>(an_b, ah_b, aw_b, pbn);
    ab_kernel<<<(HEADS * AGENTS * NTOK + 255) / 256, 256, 0, stream>>>(na_b, ha_b, wa_b, abT);
    // 4. fused agent-attn + q-attn + dwc -> bf16 rows 1..1024 of xbf
    fused_attn<<<BATCH * HEADS, 512, 0, stream>>>(qkvb, agents, pbn, abT, dwc_w, dwc_b, xbf);
    // 5. out = fused @ proj_w^T + proj_b  (M=32800, N=256, K=256)
    gemm_bf16<<<dim3(257, 2), 256, 0, stream>>>(xbf, pwbf, out, nullptr, 32800, 256, 256, proj_b, 0);
}

// Round 16
// 128.070 us; speedup vs baseline: 1.0632x; 1.0587x over previous
//
#include <hip/hip_runtime.h>
#include <hip/hip_bf16.h>

// Problem constants
#define BATCH 32
#define NTOK 1024          // 32x32
#define CH 256
#define HEADS 8
#define HD 32
#define AGENTS 49
#define WIN 32
#define QKV_N 768
#define SCALE 0.17677669529663687f   // 1/sqrt(32)

typedef unsigned short u16;
typedef __attribute__((ext_vector_type(2))) unsigned short u16x2;
typedef __attribute__((ext_vector_type(8))) unsigned short u16x8;
typedef __attribute__((ext_vector_type(8))) short short8;
typedef __attribute__((ext_vector_type(4))) float f32x4;

__device__ __forceinline__ void gload_lds16(const void* g, const void* l) {
    __builtin_amdgcn_global_load_lds(
        (const __attribute__((address_space(1))) unsigned int*)g,
        (__attribute__((address_space(3))) unsigned int*)l, 16, 0, 0);
}

__device__ __forceinline__ u16 f2bf1(float f) {
    unsigned u = __builtin_bit_cast(unsigned, f);
    u += 0x7fffu + ((u >> 16) & 1u);
    return (u16)(u >> 16);
}
__device__ __forceinline__ float bf2f(u16 v) {
    unsigned u = ((unsigned)v) << 16;
    return __builtin_bit_cast(float, u);
}

// ---------------- fp32 -> bf16 conversion, 8 elems/thread ----------------
__global__ void f2bf_kernel(const float* __restrict__ in, u16* __restrict__ out, int n8) {
    int i = blockIdx.x * 256 + threadIdx.x;
    if (i >= n8) return;
    float4 v0 = ((const float4*)in)[i * 2];
    float4 v1 = ((const float4*)in)[i * 2 + 1];
    u16x8 o;
    o[0] = f2bf1(v0.x); o[1] = f2bf1(v0.y); o[2] = f2bf1(v0.z); o[3] = f2bf1(v0.w);
    o[4] = f2bf1(v1.x); o[5] = f2bf1(v1.y); o[6] = f2bf1(v1.z); o[7] = f2bf1(v1.w);
    ((u16x8*)out)[i] = o;
}

// ---------------- bf16 MFMA GEMM: C[M,N] = A[M,K] @ B[N,K]^T (+bias) ----------------
__global__ __launch_bounds__(256) void gemm_bf16(const u16* __restrict__ A,
                                                 const u16* __restrict__ B,
                                                 float* __restrict__ C,
                                                 u16* __restrict__ C16,
                                                 int M, int N, int K,
                                                 const float* __restrict__ bias,
                                                 int amode) {
    __shared__ u16 As[128 * 32];
    __shared__ u16 Bs[128 * 32];
    const int tid = threadIdx.x;
    const int lane = tid & 63;
    const int wid = tid >> 6;
    const int row0 = blockIdx.x * 128, col0 = blockIdx.y * 128;
    const int wr = wid >> 1, wc = wid & 1;
    const int fr = lane & 15, fq = lane >> 4;

    f32x4 acc[4][4];
#pragma unroll
    for (int m = 0; m < 4; ++m)
#pragma unroll
        for (int n = 0; n < 4; ++n) acc[m][n] = (f32x4)(0.f);

    for (int k0 = 0; k0 < K; k0 += 32) {
#pragma unroll
        for (int r = 0; r < 2; ++r) {
            int trow = (tid >> 2) + r * 64;
            int tcol = (tid & 3) * 8;
            size_t aoff;
            int grow = row0 + trow;
            if (amode == 1) {
                int bb = grow >> 10, nn = grow & 1023;
                aoff = ((size_t)(bb * 1025 + nn + 1)) * 256 + (size_t)(k0 + tcol);
            } else {
                if (grow >= M) grow = M - 1;
                aoff = (size_t)grow * K + (size_t)(k0 + tcol);
            }
            gload_lds16(A + aoff, (const char*)As + wid * 1024 + r * 4096);
            int brow = col0 + trow;
            gload_lds16(B + (size_t)brow * K + (size_t)(k0 + tcol),
                        (const char*)Bs + wid * 1024 + r * 4096);
        }
        __syncthreads();

        short8 af[4], bf[4];
#pragma unroll
        for (int m = 0; m < 4; ++m)
            af[m] = *(const short8*)&As[(wr * 64 + m * 16 + fr) * 32 + fq * 8];
#pragma unroll
        for (int n = 0; n < 4; ++n)
            bf[n] = *(const short8*)&Bs[(wc * 64 + n * 16 + fr) * 32 + fq * 8];
#pragma unroll
        for (int m = 0; m < 4; ++m)
#pragma unroll
            for (int n = 0; n < 4; ++n)
                acc[m][n] = __builtin_amdgcn_mfma_f32_16x16x32_bf16(af[m], bf[n], acc[m][n], 0, 0, 0);
        __syncthreads();
    }

#pragma unroll
    for (int m = 0; m < 4; ++m) {
#pragma unroll
        for (int j = 0; j < 4; ++j) {
            int row = row0 + wr * 64 + m * 16 + fq * 4 + j;
            if (row < M) {
#pragma unroll
                for (int n = 0; n < 4; ++n) {
                    int col = col0 + wc * 64 + n * 16 + fr;
                    float v = acc[m][n][j];
                    if (bias) v += bias[col];
                    if (C16) C16[(size_t)row * N + col] = f2bf1(v);
                    else     C[(size_t)row * N + col] = v;
                }
            }
        }
    }
}

// ------- adaptive avg pool of q (bf16) -> agents (b,49,256) f32 -------
__global__ __launch_bounds__(256) void pool_kernel(const u16* __restrict__ qkvb,
                                                   float* __restrict__ agents) {
    int b = blockIdx.x / 7, py = blockIdx.x % 7;
    int ch = threadIdx.x;
    int ys = py * 32 / 7, ye = ((py + 1) * 32 + 6) / 7;
    float acc[7];
#pragma unroll
    for (int i = 0; i < 7; ++i) acc[i] = 0.f;
    for (int y = ys; y < ye; ++y) {
        const u16* rowp = qkvb + ((size_t)(b * NTOK + y * 32)) * QKV_N + ch;
#pragma unroll
        for (int PX = 0; PX < 7; ++PX) {
            const int xs = PX * 32 / 7, xe = ((PX + 1) * 32 + 6) / 7;
            float s = 0.f;
            for (int x = xs; x < xe; ++x) s += bf2f(rowp[(size_t)x * QKV_N]);
            acc[PX] += s;
        }
    }
    int rcnt = ye - ys;
#pragma unroll
    for (int PX = 0; PX < 7; ++PX) {
        const int xs = PX * 32 / 7, xe = ((PX + 1) * 32 + 6) / 7;
        agents[((size_t)(b * AGENTS + py * 7 + PX)) * CH + ch] =
            acc[PX] / (float)(rcnt * (xe - xs));
    }
}

// ---------------- bilinear 7x7 sample (half-pixel, clamped) ----------------
__device__ inline float bilin7(const float* __restrict__ m, float sy, float sx) {
    float fy0 = floorf(sy), fx0 = floorf(sx);
    int y0 = (int)fy0, x0 = (int)fx0;
    float fy = sy - fy0, fx = sx - fx0;
    int y0c = min(max(y0, 0), 6), y1c = min(max(y0 + 1, 0), 6);
    int x0c = min(max(x0, 0), 6), x1c = min(max(x0 + 1, 0), 6);
    float v00 = m[y0c * 7 + x0c], v01 = m[y0c * 7 + x1c];
    float v10 = m[y1c * 7 + x0c], v11 = m[y1c * 7 + x1c];
    return (1.f - fy) * ((1.f - fx) * v00 + fx * v01) + fy * ((1.f - fx) * v10 + fx * v11);
}

// pbn[h][n][64] = resize(an_bias)[h,a,y,x] + ah_bias[h,a,y] + aw_bias[h,a,x]  (n-major, a rows 49..63 zero)
__global__ void pb_kernel(const float* __restrict__ an, const float* __restrict__ ahb,
                          const float* __restrict__ awb, float* __restrict__ pbn) {
    int h = blockIdx.x >> 6, a = blockIdx.x & 63;
    if (a >= AGENTS) {
        for (int n = threadIdx.x; n < NTOK; n += 256)
            pbn[((size_t)(h * NTOK + n)) * 64 + a] = 0.f;
        return;
    }
    const float* m = an + (h * AGENTS + a) * 49;
    for (int n = threadIdx.x; n < NTOK; n += 256) {
        int y = n >> 5, x = n & 31;
        float v = bilin7(m, (y + 0.5f) * (7.f / 32.f) - 0.5f, (x + 0.5f) * (7.f / 32.f) - 0.5f);
        v += ahb[(h * AGENTS + a) * 32 + y] + awb[(h * AGENTS + a) * 32 + x];
        pbn[((size_t)(h * NTOK + n)) * 64 + a] = v;
    }
}

// abT[h][a][n] = resize(na_bias)[h,a,y,x] + ha_bias[h,y,a] + wa_bias[h,x,a]   (a-major)
__global__ void ab_kernel(const float* __restrict__ na, const float* __restrict__ hab,
                          const float* __restrict__ wab, float* __restrict__ abT) {
    int idx = blockIdx.x * 256 + threadIdx.x;          // = (h*49 + a)*1024 + n
    if (idx >= HEADS * AGENTS * NTOK) return;
    int h = idx / (AGENTS * NTOK);
    int r = idx % (AGENTS * NTOK);
    int a = r / NTOK, n = r % NTOK;
    int y = n >> 5, x = n & 31;
    const float* m = na + (h * AGENTS + a) * 49;
    float v = bilin7(m, (y + 0.5f) * (7.f / 32.f) - 0.5f, (x + 0.5f) * (7.f / 32.f) - 0.5f);
    v += hab[(h * 32 + y) * AGENTS + a] + wab[(h * 32 + x) * AGENTS + a];
    abT[idx] = v;
}

// ============ fused attention: agent-attn (MFMA) + q-attn (MFMA) + dwc ============
// grid = 256 (b,h); 512 threads = 8 waves. Phase 1 = agent attention -> avT in LDS.
// Phase 2 = q attention + depthwise conv; V taps and PV B-operand from the Vt transpose.
// VTP=1038: row stride 519 dw, 519%32=7 -> d-rows land on distinct banks.
// OSTR=36: O-write 2-way (free); merge read d-fastest (conflict-free).
// NOTE: NO s_setprio here — R15 measured it at +7 us (write-allocate amplification via
// scheduler-perturbed L2 eviction timing; phases are __syncthreads-lockstep, m190 case).
#define VTP 1038
#define OSTR 36
__global__ __launch_bounds__(512) void fused_attn(const u16* __restrict__ qkvb,
                                                  const float* __restrict__ agents,
                                                  const float* __restrict__ pbn,
                                                  const float* __restrict__ abT,
                                                  const float* __restrict__ dwc_w,
                                                  const float* __restrict__ dwc_b,
                                                  u16* __restrict__ outbf) {
    int b = blockIdx.x >> 3, h = blockIdx.x & 7;
    int tid = threadIdx.x, lane = tid & 63, w = tid >> 6;
    const int fr = lane & 15, fq = lane >> 4;

    __shared__ u16 ah_lds[64 * 32];       // 4 KB, scale folded, rows 49..63 zero
    __shared__ u16 Vt[32 * VTP];          // 66.4 KB  V^T [dim][token] (both phases)
    __shared__ float PO[8][2304];         // 73.7 KB  per-wave P/O scratch (O: 64 x OSTR=36)
    __shared__ float lsum_lds[8][64];     // 2 KB
    __shared__ u16 avT[32][72];           // 4.6 KB  agent_v^T bf16 (phase 2)
    __shared__ float w9[9][32];           // 1.15 KB
    __shared__ float bia[32];

    u16*   Pw = (u16*)&PO[w][0];
    float* Ow = &PO[w][0];

    // ---- staging (cooperative) ----
    for (int li = tid; li < 64 * 32; li += 512) {
        int a = li >> 5, d = li & 31;
        float v = (a < AGENTS) ? agents[((size_t)(b * AGENTS + a)) * CH + h * HD + d] * SCALE : 0.f;
        ah_lds[li] = f2bf1(v);
    }
    // V^T staging: token-pair repack -> u16x2 writes (<=2-way banked)
    for (int li = tid; li < 512 * 4; li += 512) {
        int p = li >> 2, d8 = (li & 3) * 8;       // tokens 2p,2p+1 ; dims d8..d8+7
        const u16* g0 = &qkvb[((size_t)(b * NTOK + 2 * p)) * QKV_N + 2 * CH + h * HD + d8];
        u16x8 va = *(const u16x8*)g0;
        u16x8 vb = *(const u16x8*)(g0 + QKV_N);
#pragma unroll
        for (int j = 0; j < 8; ++j) {
            u16x2 w2; w2[0] = va[j]; w2[1] = vb[j];
            *(u16x2*)&Vt[(d8 + j) * VTP + 2 * p] = w2;
        }
    }
    for (int li = tid; li < 288; li += 512) {
        int t = li >> 5, d = li & 31;
        w9[t][d] = dwc_w[(h * HD + d) * 9 + t];
    }
    if (tid < 32) bia[tid] = dwc_b[h * HD + tid];
    __syncthreads();

    // ================= phase 1: agent attention =================
    short8 ahf[4];
#pragma unroll
    for (int mt = 0; mt < 4; ++mt)
        ahf[mt] = *(const short8*)&ah_lds[(mt * 16 + fr) * 32 + fq * 8];

    // preload K fragments for BOTH chunks
    short8 kf[2][4];
#pragma unroll
    for (int c2 = 0; c2 < 2; ++c2)
#pragma unroll
        for (int nt = 0; nt < 4; ++nt)
            kf[c2][nt] = *(const short8*)&qkvb[((size_t)(b * NTOK + w * 128 + c2 * 64 + nt * 16 + fr)) * QKV_N + CH + h * HD + fq * 8];

    float lsum[4][4];
#pragma unroll
    for (int mt = 0; mt < 4; ++mt)
#pragma unroll
        for (int j = 0; j < 4; ++j) lsum[mt][j] = 0.f;
    f32x4 accA[4][2];
#pragma unroll
    for (int mt = 0; mt < 4; ++mt)
#pragma unroll
        for (int ntd = 0; ntd < 2; ++ntd) accA[mt][ntd] = (f32x4)(0.f);

    const float* pbnh = pbn + (size_t)h * NTOK * 64;

#pragma unroll
    for (int c2 = 0; c2 < 2; ++c2) {
        int tb = w * 128 + c2 * 64;

        f32x4 pbq[2][4];
#pragma unroll
        for (int nt = 0; nt < 4; ++nt)
            pbq[0][nt] = *(const f32x4*)&pbnh[(size_t)(tb + nt * 16 + fr) * 64 + fq * 4];

#pragma unroll
        for (int mt = 0; mt < 4; ++mt) {
            f32x4 accS[4];
#pragma unroll
            for (int nt = 0; nt < 4; ++nt)
                accS[nt] = __builtin_amdgcn_mfma_f32_16x16x32_bf16(ahf[mt], kf[c2][nt], (f32x4)(0.f), 0, 0, 0);
            if (mt < 3) {
#pragma unroll
                for (int nt = 0; nt < 4; ++nt)
                    pbq[(mt + 1) & 1][nt] = *(const f32x4*)&pbnh[(size_t)(tb + nt * 16 + fr) * 64 + (mt + 1) * 16 + fq * 4];
            }
#pragma unroll
            for (int j = 0; j < 4; ++j) {
                int a = mt * 16 + fq * 4 + j;
#pragma unroll
                for (int nt = 0; nt < 4; ++nt) {
                    float e = __expf(accS[nt][j] + pbq[mt & 1][nt][j]);
                    lsum[mt][j] += e;
                    Pw[a * 72 + nt * 16 + fr] = f2bf1(e);
                }
            }
        }

        short8 pf[4][2], vf[2][2];
#pragma unroll
        for (int mt = 0; mt < 4; ++mt)
#pragma unroll
            for (int kc = 0; kc < 2; ++kc)
                pf[mt][kc] = *(const short8*)&Pw[(mt * 16 + fr) * 72 + kc * 32 + fq * 8];
#pragma unroll
        for (int ntd = 0; ntd < 2; ++ntd)
#pragma unroll
            for (int kc = 0; kc < 2; ++kc)
                vf[ntd][kc] = *(const short8*)&Vt[(ntd * 16 + fr) * VTP + tb + kc * 32 + fq * 8];

#pragma unroll
        for (int mt = 0; mt < 4; ++mt)
#pragma unroll
            for (int kc = 0; kc < 2; ++kc)
#pragma unroll
                for (int ntd = 0; ntd < 2; ++ntd)
                    accA[mt][ntd] = __builtin_amdgcn_mfma_f32_16x16x32_bf16(pf[mt][kc], vf[ntd][kc], accA[mt][ntd], 0, 0, 0);
    }

#pragma unroll
    for (int mt = 0; mt < 4; ++mt)
#pragma unroll
        for (int j = 0; j < 4; ++j) {
            float s = lsum[mt][j];
            s += __shfl_xor(s, 1);
            s += __shfl_xor(s, 2);
            s += __shfl_xor(s, 4);
            s += __shfl_xor(s, 8);
            lsum[mt][j] = s;
        }
    if (fr == 0) {
#pragma unroll
        for (int mt = 0; mt < 4; ++mt)
#pragma unroll
            for (int j = 0; j < 4; ++j)
                lsum_lds[w][mt * 16 + fq * 4 + j] = lsum[mt][j];
    }

    // TBAA guard: float stores below alias the u16 P reads above (type-punned region)
    asm volatile("s_waitcnt lgkmcnt(0)" ::: "memory");
    __builtin_amdgcn_sched_barrier(0);

#pragma unroll
    for (int mt = 0; mt < 4; ++mt)
#pragma unroll
        for (int ntd = 0; ntd < 2; ++ntd)
#pragma unroll
            for (int j = 0; j < 4; ++j)
                Ow[(mt * 16 + fq * 4 + j) * OSTR + ntd * 16 + fr] = accA[mt][ntd][j];

    __syncthreads();

    // merge 8 waves -> avT. d fastest -> each 32-lane group sweeps 32 banks (conflict-free).
    for (int li = tid; li < 64 * HD; li += 512) {
        int d = li & 31, a = li >> 5;
        float val = 0.f;
        if (a < AGENTS) {
            float L = 0.f, o = 0.f;
#pragma unroll
            for (int ww = 0; ww < 8; ++ww) {
                o += PO[ww][a * OSTR + d];
                L += lsum_lds[ww][a];
            }
            val = o / L;
        }
        avT[d][a] = f2bf1(val);
    }
    __syncthreads();

    // ================= phase 2: q attention + dwc =================
    short8 avf[2][2];
#pragma unroll
    for (int ntd = 0; ntd < 2; ++ntd)
#pragma unroll
        for (int kc = 0; kc < 2; ++kc)
            avf[ntd][kc] = *(const short8*)&avT[ntd * 16 + fr][kc * 32 + fq * 8];

    // preload ALL Q fragments
    short8 qf2[4][2];
#pragma unroll
    for (int hh = 0; hh < 4; ++hh)
#pragma unroll
        for (int mt2 = 0; mt2 < 2; ++mt2)
            qf2[hh][mt2] = *(const short8*)(qkvb + ((size_t)(b * NTOK + w * 128 + hh * 32 + mt2 * 16 + fr)) * QKV_N + h * HD + fq * 8);

    const float* abTh = abT + (size_t)h * AGENTS * NTOK;

#pragma unroll
    for (int hh = 0; hh < 4; ++hh) {
        int hb = w * 128 + hh * 32;

        f32x4 abv[2][4];
#pragma unroll
        for (int mt2 = 0; mt2 < 2; ++mt2)
#pragma unroll
            for (int nt = 0; nt < 4; ++nt)
                abv[mt2][nt] = *(const f32x4*)&abTh[(size_t)min(nt * 16 + fr, AGENTS - 1) * NTOK + hb + mt2 * 16 + fq * 4];

#pragma unroll
        for (int mt2 = 0; mt2 < 2; ++mt2) {
            f32x4 accS[4];
#pragma unroll
            for (int nt = 0; nt < 4; ++nt)
                accS[nt] = __builtin_amdgcn_mfma_f32_16x16x32_bf16(qf2[hh][mt2], ahf[nt], (f32x4)(0.f), 0, 0, 0);

            float e[4][4];   // [j][nt]
            float ps[4];
#pragma unroll
            for (int j = 0; j < 4; ++j) ps[j] = 0.f;
#pragma unroll
            for (int j = 0; j < 4; ++j) {
#pragma unroll
                for (int nt = 0; nt < 4; ++nt) {
                    int a = nt * 16 + fr;
                    float s = accS[nt][j] + abv[mt2][nt][j];
                    float ev = (a < AGENTS) ? __expf(s) : 0.f;
                    e[j][nt] = ev;
                    ps[j] += ev;
                }
            }
#pragma unroll
            for (int j = 0; j < 4; ++j) {
                ps[j] += __shfl_xor(ps[j], 1);
                ps[j] += __shfl_xor(ps[j], 2);
                ps[j] += __shfl_xor(ps[j], 4);
                ps[j] += __shfl_xor(ps[j], 8);
            }
#pragma unroll
            for (int j = 0; j < 4; ++j) {
                float inv = 1.f / ps[j];
                int tl = mt2 * 16 + fq * 4 + j;
#pragma unroll
                for (int nt = 0; nt < 4; ++nt)
                    Pw[tl * 68 + nt * 16 + fr] = f2bf1(e[j][nt] * inv);
            }
        }

        short8 pf2[2][2];
#pragma unroll
        for (int mt2 = 0; mt2 < 2; ++mt2)
#pragma unroll
            for (int kc = 0; kc < 2; ++kc)
                pf2[mt2][kc] = *(const short8*)&Pw[(mt2 * 16 + fr) * 68 + kc * 32 + fq * 8];

        f32x4 accO[2][2];
#pragma unroll
        for (int mt2 = 0; mt2 < 2; ++mt2)
#pragma unroll
            for (int ntd = 0; ntd < 2; ++ntd) accO[mt2][ntd] = (f32x4)(0.f);
#pragma unroll
        for (int mt2 = 0; mt2 < 2; ++mt2)
#pragma unroll
            for (int kc = 0; kc < 2; ++kc)
#pragma unroll
                for (int ntd = 0; ntd < 2; ++ntd)
                    accO[mt2][ntd] = __builtin_amdgcn_mfma_f32_16x16x32_bf16(pf2[mt2][kc], avf[ntd][kc], accO[mt2][ntd], 0, 0, 0);

        // fused dwc + bias + bf16 store (C-layout epilogue); V taps via u16x2 spans
        int y = w * 4 + hh;
#pragma unroll
        for (int ntd = 0; ntd < 2; ++ntd) {
            int d = ntd * 16 + fr;
            float wv[9];
#pragma unroll
            for (int t = 0; t < 9; ++t) wv[t] = w9[t][d];
            float bv = bia[d];
            const u16* Vd = &Vt[d * VTP];
#pragma unroll
            for (int mt2 = 0; mt2 < 2; ++mt2) {
                int x0 = mt2 * 16 + fq * 4;
                float sp[3][8];      // tokens x0-2 .. x0+5 per dy row
#pragma unroll
                for (int dy = 0; dy < 3; ++dy) {
                    int yy = y - 1 + dy;
                    if (yy >= 0 && yy < 32) {
                        int base = yy * 32 + x0 - 2;     // even -> 4B-aligned
                        u16x2 r0 = *(const u16x2*)&Vd[base];
                        u16x2 r1 = *(const u16x2*)&Vd[base + 2];
                        u16x2 r2 = *(const u16x2*)&Vd[base + 4];
                        u16x2 r3 = *(const u16x2*)&Vd[base + 6];
                        sp[dy][0] = bf2f(r0[0]); sp[dy][1] = bf2f(r0[1]);
                        sp[dy][2] = bf2f(r1[0]); sp[dy][3] = bf2f(r1[1]);
                        sp[dy][4] = bf2f(r2[0]); sp[dy][5] = bf2f(r2[1]);
                        sp[dy][6] = bf2f(r3[0]); sp[dy][7] = bf2f(r3[1]);
                    } else {
#pragma unroll
                        for (int k = 0; k < 8; ++k) sp[dy][k] = 0.f;
                    }
                }
                float vv[3][6];      // xx = x0-1+k, masked at image edges
#pragma unroll
                for (int dy = 0; dy < 3; ++dy)
#pragma unroll
                    for (int k = 0; k < 6; ++k) {
                        int xx = x0 - 1 + k;
                        vv[dy][k] = (xx >= 0 && xx < 32) ? sp[dy][k + 1] : 0.f;
                    }
#pragma unroll
                for (int j = 0; j < 4; ++j) {
                    float o = accO[mt2][ntd][j] + bv;
#pragma unroll
                    for (int dy = 0; dy < 3; ++dy)
#pragma unroll
                        for (int dx = 0; dx < 3; ++dx)
                            o = fmaf(wv[dy * 3 + dx], vv[dy][j + dx], o);
                    int n = y * 32 + x0 + j;
                    outbf[((size_t)(b * 1025 + 1 + n)) * CH + h * HD + d] = f2bf1(o);
                }
            }
        }
    }
}
#undef VTP
#undef OSTR

extern "C" void kernel_launch(void* const* d_in, const int* in_sizes, int n_in,
                              void* d_out, int out_size, void* d_ws, size_t ws_size,
                              hipStream_t stream) {
    const float* x      = (const float*)d_in[0];
    const float* qkv_w  = (const float*)d_in[1];
    const float* proj_w = (const float*)d_in[2];
    const float* proj_b = (const float*)d_in[3];
    const float* dwc_w  = (const float*)d_in[4];
    const float* dwc_b  = (const float*)d_in[5];
    const float* an_b   = (const float*)d_in[6];
    const float* ah_b   = (const float*)d_in[7];
    const float* aw_b   = (const float*)d_in[8];
    const float* na_b   = (const float*)d_in[9];
    const float* ha_b   = (const float*)d_in[10];
    const float* wa_b   = (const float*)d_in[11];
    float* out = (float*)d_out;

    float* ws      = (float*)d_ws;
    u16*   qkvb    = (u16*)ws;                 // 25,165,824 u16 (bf16 qkv)
    float* agents  = ws + 12582912;            // 401,408 f
    float* pbn     = agents + 401408;          // 524,288 f  (n-major [h][n][64])
    float* abT     = pbn + 524288;             // 401,408 f  (a-major [h][a][n])
    u16* xbf  = (u16*)(abT + 401408);          // 8,396,800 u16 (x bf16 -> fused bf16 rows)
    u16* qwbf = xbf + 8396800;                 // 196,608 u16
    u16* pwbf = qwbf + 196608;                 // 65,536 u16

    // conversions (xbf rows b*1025 keep bf16 cls tokens for the proj GEMM; the full-x
    // pass also pre-writes every xbf line so fused_attn's partial-line stores hit
    // resident lines instead of RMW write-allocating — R14 lesson)
    f2bf_kernel<<<4100, 256, 0, stream>>>(x, xbf, 8396800 / 8);
    f2bf_kernel<<<96, 256, 0, stream>>>(qkv_w, qwbf, 196608 / 8);
    f2bf_kernel<<<32, 256, 0, stream>>>(proj_w, pwbf, 65536 / 8);
    // 1. qkv(bf16) = xs @ qkv_w^T   (M=32768, N=768, K=256)
    gemm_bf16<<<dim3(256, 6), 256, 0, stream>>>(xbf, qwbf, nullptr, qkvb, 32768, 768, 256, nullptr, 1);
    // 2. agent pooling of q
    pool_kernel<<<BATCH * 7, 256, 0, stream>>>(qkvb, agents);
    // 3. position biases (pbn n-major with zero pad rows; abT a-major)
    pb_kernel<<<HEADS * 64, 256, 0, stream>>>(an_b, ah_b, aw_b, pbn);
    ab_kernel<<<(HEADS * AGENTS * NTOK + 255) / 256, 256, 0, stream>>>(na_b, ha_b, wa_b, abT);
    // 4. fused agent-attn + q-attn + dwc -> bf16 rows 1..1024 of xbf
    fused_attn<<<BATCH * HEADS, 512, 0, stream>>>(qkvb, agents, pbn, abT, dwc_w, dwc_b, xbf);
    // 5. out = fused @ proj_w^T + proj_b  (M=32800, N=256, K=256)
    gemm_bf16<<<dim3(257, 2), 256, 0, stream>>>(xbf, pwbf, out, nullptr, 32800, 256, 256, proj_b, 0);
}

// Round 17
// 125.465 us; speedup vs baseline: 1.0853x; 1.0208x over previous
//
#include <hip/hip_runtime.h>
#include <hip/hip_bf16.h>

// Problem constants
#define BATCH 32
#define NTOK 1024          // 32x32
#define CH 256
#define HEADS 8
#define HD 32
#define AGENTS 49
#define WIN 32
#define QKV_N 768
#define SCALE 0.17677669529663687f   // 1/sqrt(32)

typedef unsigned short u16;
typedef __attribute__((ext_vector_type(2))) unsigned short u16x2;
typedef __attribute__((ext_vector_type(8))) unsigned short u16x8;
typedef __attribute__((ext_vector_type(8))) short short8;
typedef __attribute__((ext_vector_type(4))) float f32x4;

__device__ __forceinline__ void gload_lds16(const void* g, const void* l) {
    __builtin_amdgcn_global_load_lds(
        (const __attribute__((address_space(1))) unsigned int*)g,
        (__attribute__((address_space(3))) unsigned int*)l, 16, 0, 0);
}

__device__ __forceinline__ u16 f2bf1(float f) {
    unsigned u = __builtin_bit_cast(unsigned, f);
    u += 0x7fffu + ((u >> 16) & 1u);
    return (u16)(u >> 16);
}
__device__ __forceinline__ float bf2f(u16 v) {
    unsigned u = ((unsigned)v) << 16;
    return __builtin_bit_cast(float, u);
}

// ---------------- fp32 -> bf16 conversion, 8 elems/thread ----------------
__global__ void f2bf_kernel(const float* __restrict__ in, u16* __restrict__ out, int n8) {
    int i = blockIdx.x * 256 + threadIdx.x;
    if (i >= n8) return;
    float4 v0 = ((const float4*)in)[i * 2];
    float4 v1 = ((const float4*)in)[i * 2 + 1];
    u16x8 o;
    o[0] = f2bf1(v0.x); o[1] = f2bf1(v0.y); o[2] = f2bf1(v0.z); o[3] = f2bf1(v0.w);
    o[4] = f2bf1(v1.x); o[5] = f2bf1(v1.y); o[6] = f2bf1(v1.z); o[7] = f2bf1(v1.w);
    ((u16x8*)out)[i] = o;
}

// both weight matrices in one launch (blocks 0..95: qkv_w; 96..127: proj_w)
__global__ void f2bf_w(const float* __restrict__ qkv_w, const float* __restrict__ proj_w,
                       u16* __restrict__ qwbf, u16* __restrict__ pwbf) {
    int blk = blockIdx.x;
    const float* in; u16* out; int i;
    if (blk < 96) { in = qkv_w;  out = qwbf; i = blk * 256 + threadIdx.x; }
    else          { in = proj_w; out = pwbf; i = (blk - 96) * 256 + threadIdx.x; }
    float4 v0 = ((const float4*)in)[i * 2];
    float4 v1 = ((const float4*)in)[i * 2 + 1];
    u16x8 o;
    o[0] = f2bf1(v0.x); o[1] = f2bf1(v0.y); o[2] = f2bf1(v0.z); o[3] = f2bf1(v0.w);
    o[4] = f2bf1(v1.x); o[5] = f2bf1(v1.y); o[6] = f2bf1(v1.z); o[7] = f2bf1(v1.w);
    ((u16x8*)out)[i] = o;
}

// ---------------- bf16 MFMA GEMM: C[M,N] = A[M,K] @ B[N,K]^T (+bias) ----------------
__global__ __launch_bounds__(256) void gemm_bf16(const u16* __restrict__ A,
                                                 const u16* __restrict__ B,
                                                 float* __restrict__ C,
                                                 u16* __restrict__ C16,
                                                 int M, int N, int K,
                                                 const float* __restrict__ bias,
                                                 int amode) {
    __shared__ u16 As[128 * 32];
    __shared__ u16 Bs[128 * 32];
    const int tid = threadIdx.x;
    const int lane = tid & 63;
    const int wid = tid >> 6;
    const int row0 = blockIdx.x * 128, col0 = blockIdx.y * 128;
    const int wr = wid >> 1, wc = wid & 1;
    const int fr = lane & 15, fq = lane >> 4;

    f32x4 acc[4][4];
#pragma unroll
    for (int m = 0; m < 4; ++m)
#pragma unroll
        for (int n = 0; n < 4; ++n) acc[m][n] = (f32x4)(0.f);

    for (int k0 = 0; k0 < K; k0 += 32) {
#pragma unroll
        for (int r = 0; r < 2; ++r) {
            int trow = (tid >> 2) + r * 64;
            int tcol = (tid & 3) * 8;
            size_t aoff;
            int grow = row0 + trow;
            if (amode == 1) {
                int bb = grow >> 10, nn = grow & 1023;
                aoff = ((size_t)(bb * 1025 + nn + 1)) * 256 + (size_t)(k0 + tcol);
            } else {
                if (grow >= M) grow = M - 1;
                aoff = (size_t)grow * K + (size_t)(k0 + tcol);
            }
            gload_lds16(A + aoff, (const char*)As + wid * 1024 + r * 4096);
            int brow = col0 + trow;
            gload_lds16(B + (size_t)brow * K + (size_t)(k0 + tcol),
                        (const char*)Bs + wid * 1024 + r * 4096);
        }
        __syncthreads();

        short8 af[4], bf[4];
#pragma unroll
        for (int m = 0; m < 4; ++m)
            af[m] = *(const short8*)&As[(wr * 64 + m * 16 + fr) * 32 + fq * 8];
#pragma unroll
        for (int n = 0; n < 4; ++n)
            bf[n] = *(const short8*)&Bs[(wc * 64 + n * 16 + fr) * 32 + fq * 8];
#pragma unroll
        for (int m = 0; m < 4; ++m)
#pragma unroll
            for (int n = 0; n < 4; ++n)
                acc[m][n] = __builtin_amdgcn_mfma_f32_16x16x32_bf16(af[m], bf[n], acc[m][n], 0, 0, 0);
        __syncthreads();
    }

#pragma unroll
    for (int m = 0; m < 4; ++m) {
#pragma unroll
        for (int j = 0; j < 4; ++j) {
            int row = row0 + wr * 64 + m * 16 + fq * 4 + j;
            if (row < M) {
#pragma unroll
                for (int n = 0; n < 4; ++n) {
                    int col = col0 + wc * 64 + n * 16 + fr;
                    float v = acc[m][n][j];
                    if (bias) v += bias[col];
                    if (C16) C16[(size_t)row * N + col] = f2bf1(v);
                    else     C[(size_t)row * N + col] = v;
                }
            }
        }
    }
}

// ------- adaptive avg pool of q (bf16) -> agents (b,49,256) f32 -------
__global__ __launch_bounds__(256) void pool_kernel(const u16* __restrict__ qkvb,
                                                   float* __restrict__ agents) {
    int b = blockIdx.x / 7, py = blockIdx.x % 7;
    int ch = threadIdx.x;
    int ys = py * 32 / 7, ye = ((py + 1) * 32 + 6) / 7;
    float acc[7];
#pragma unroll
    for (int i = 0; i < 7; ++i) acc[i] = 0.f;
    for (int y = ys; y < ye; ++y) {
        const u16* rowp = qkvb + ((size_t)(b * NTOK + y * 32)) * QKV_N + ch;
#pragma unroll
        for (int PX = 0; PX < 7; ++PX) {
            const int xs = PX * 32 / 7, xe = ((PX + 1) * 32 + 6) / 7;
            float s = 0.f;
            for (int x = xs; x < xe; ++x) s += bf2f(rowp[(size_t)x * QKV_N]);
            acc[PX] += s;
        }
    }
    int rcnt = ye - ys;
#pragma unroll
    for (int PX = 0; PX < 7; ++PX) {
        const int xs = PX * 32 / 7, xe = ((PX + 1) * 32 + 6) / 7;
        agents[((size_t)(b * AGENTS + py * 7 + PX)) * CH + ch] =
            acc[PX] / (float)(rcnt * (xe - xs));
    }
}

// ---------------- bilinear 7x7 sample (half-pixel, clamped) ----------------
__device__ inline float bilin7(const float* __restrict__ m, float sy, float sx) {
    float fy0 = floorf(sy), fx0 = floorf(sx);
    int y0 = (int)fy0, x0 = (int)fx0;
    float fy = sy - fy0, fx = sx - fx0;
    int y0c = min(max(y0, 0), 6), y1c = min(max(y0 + 1, 0), 6);
    int x0c = min(max(x0, 0), 6), x1c = min(max(x0 + 1, 0), 6);
    float v00 = m[y0c * 7 + x0c], v01 = m[y0c * 7 + x1c];
    float v10 = m[y1c * 7 + x0c], v11 = m[y1c * 7 + x1c];
    return (1.f - fy) * ((1.f - fx) * v00 + fx * v01) + fy * ((1.f - fx) * v10 + fx * v11);
}

// merged bias kernel:
// blocks [0, 512):  pbn[h][n][64] (n-major, a rows 49..63 zero)
// blocks [512, 2080): abT[h][a][n] (a-major)
__global__ void bias_kernel(const float* __restrict__ an, const float* __restrict__ ahb,
                            const float* __restrict__ awb, const float* __restrict__ na,
                            const float* __restrict__ hab, const float* __restrict__ wab,
                            float* __restrict__ pbn, float* __restrict__ abT) {
    int blk = blockIdx.x;
    if (blk < HEADS * 64) {
        int h = blk >> 6, a = blk & 63;
        if (a >= AGENTS) {
            for (int n = threadIdx.x; n < NTOK; n += 256)
                pbn[((size_t)(h * NTOK + n)) * 64 + a] = 0.f;
            return;
        }
        const float* m = an + (h * AGENTS + a) * 49;
        for (int n = threadIdx.x; n < NTOK; n += 256) {
            int y = n >> 5, x = n & 31;
            float v = bilin7(m, (y + 0.5f) * (7.f / 32.f) - 0.5f, (x + 0.5f) * (7.f / 32.f) - 0.5f);
            v += ahb[(h * AGENTS + a) * 32 + y] + awb[(h * AGENTS + a) * 32 + x];
            pbn[((size_t)(h * NTOK + n)) * 64 + a] = v;
        }
    } else {
        int idx = (blk - HEADS * 64) * 256 + threadIdx.x;   // = (h*49 + a)*1024 + n
        if (idx >= HEADS * AGENTS * NTOK) return;
        int h = idx / (AGENTS * NTOK);
        int r = idx % (AGENTS * NTOK);
        int a = r / NTOK, n = r % NTOK;
        int y = n >> 5, x = n & 31;
        const float* m = na + (h * AGENTS + a) * 49;
        float v = bilin7(m, (y + 0.5f) * (7.f / 32.f) - 0.5f, (x + 0.5f) * (7.f / 32.f) - 0.5f);
        v += hab[(h * 32 + y) * AGENTS + a] + wab[(h * 32 + x) * AGENTS + a];
        abT[idx] = v;
    }
}

// ============ fused attention: agent-attn (MFMA) + q-attn (MFMA) + dwc ============
// grid = 256 (b,h); 512 threads = 8 waves. Phase 1 = agent attention -> avT in LDS.
// Phase 2 = q attention + depthwise conv; V taps and PV B-operand from the Vt transpose.
// VTP=1038: row stride 519 dw, 519%32=7 -> d-rows land on distinct banks.
// OSTR=36: O-write 2-way (free); merge read d-fastest (conflict-free).
// Phase 2: P double-buffered across hh (breaks WAR serialization); softmax
// normalization deferred to the epilogue (P stores unnormalized e, bounded, bf16-safe).
// NO s_setprio (R15: +7us regression, lockstep phases = m190 case).
#define VTP 1038
#define OSTR 36
__global__ __launch_bounds__(512) void fused_attn(const u16* __restrict__ qkvb,
                                                  const float* __restrict__ agents,
                                                  const float* __restrict__ pbn,
                                                  const float* __restrict__ abT,
                                                  const float* __restrict__ dwc_w,
                                                  const float* __restrict__ dwc_b,
                                                  u16* __restrict__ outbf) {
    int b = blockIdx.x >> 3, h = blockIdx.x & 7;
    int tid = threadIdx.x, lane = tid & 63, w = tid >> 6;
    const int fr = lane & 15, fq = lane >> 4;

    __shared__ u16 ah_lds[64 * 32];       // 4 KB, scale folded, rows 49..63 zero
    __shared__ u16 Vt[32 * VTP];          // 66.4 KB  V^T [dim][token] (both phases)
    __shared__ float PO[8][2304];         // 73.7 KB  per-wave P/O scratch (O: 64 x OSTR=36)
    __shared__ float lsum_lds[8][64];     // 2 KB
    __shared__ u16 avT[32][72];           // 4.6 KB  agent_v^T bf16 (phase 2)
    __shared__ float w9[9][32];           // 1.15 KB
    __shared__ float bia[32];

    u16*   Pw = (u16*)&PO[w][0];
    float* Ow = &PO[w][0];

    // ---- staging (cooperative) ----
    for (int li = tid; li < 64 * 32; li += 512) {
        int a = li >> 5, d = li & 31;
        float v = (a < AGENTS) ? agents[((size_t)(b * AGENTS + a)) * CH + h * HD + d] * SCALE : 0.f;
        ah_lds[li] = f2bf1(v);
    }
    // V^T staging: token-pair repack -> u16x2 writes (<=2-way banked)
    for (int li = tid; li < 512 * 4; li += 512) {
        int p = li >> 2, d8 = (li & 3) * 8;       // tokens 2p,2p+1 ; dims d8..d8+7
        const u16* g0 = &qkvb[((size_t)(b * NTOK + 2 * p)) * QKV_N + 2 * CH + h * HD + d8];
        u16x8 va = *(const u16x8*)g0;
        u16x8 vb = *(const u16x8*)(g0 + QKV_N);
#pragma unroll
        for (int j = 0; j < 8; ++j) {
            u16x2 w2; w2[0] = va[j]; w2[1] = vb[j];
            *(u16x2*)&Vt[(d8 + j) * VTP + 2 * p] = w2;
        }
    }
    for (int li = tid; li < 288; li += 512) {
        int t = li >> 5, d = li & 31;
        w9[t][d] = dwc_w[(h * HD + d) * 9 + t];
    }
    if (tid < 32) bia[tid] = dwc_b[h * HD + tid];
    __syncthreads();

    // ================= phase 1: agent attention =================
    short8 ahf[4];
#pragma unroll
    for (int mt = 0; mt < 4; ++mt)
        ahf[mt] = *(const short8*)&ah_lds[(mt * 16 + fr) * 32 + fq * 8];

    // preload K fragments for BOTH chunks
    short8 kf[2][4];
#pragma unroll
    for (int c2 = 0; c2 < 2; ++c2)
#pragma unroll
        for (int nt = 0; nt < 4; ++nt)
            kf[c2][nt] = *(const short8*)&qkvb[((size_t)(b * NTOK + w * 128 + c2 * 64 + nt * 16 + fr)) * QKV_N + CH + h * HD + fq * 8];

    float lsum[4][4];
#pragma unroll
    for (int mt = 0; mt < 4; ++mt)
#pragma unroll
        for (int j = 0; j < 4; ++j) lsum[mt][j] = 0.f;
    f32x4 accA[4][2];
#pragma unroll
    for (int mt = 0; mt < 4; ++mt)
#pragma unroll
        for (int ntd = 0; ntd < 2; ++ntd) accA[mt][ntd] = (f32x4)(0.f);

    const float* pbnh = pbn + (size_t)h * NTOK * 64;

#pragma unroll
    for (int c2 = 0; c2 < 2; ++c2) {
        int tb = w * 128 + c2 * 64;

        f32x4 pbq[2][4];
#pragma unroll
        for (int nt = 0; nt < 4; ++nt)
            pbq[0][nt] = *(const f32x4*)&pbnh[(size_t)(tb + nt * 16 + fr) * 64 + fq * 4];

#pragma unroll
        for (int mt = 0; mt < 4; ++mt) {
            f32x4 accS[4];
#pragma unroll
            for (int nt = 0; nt < 4; ++nt)
                accS[nt] = __builtin_amdgcn_mfma_f32_16x16x32_bf16(ahf[mt], kf[c2][nt], (f32x4)(0.f), 0, 0, 0);
            if (mt < 3) {
#pragma unroll
                for (int nt = 0; nt < 4; ++nt)
                    pbq[(mt + 1) & 1][nt] = *(const f32x4*)&pbnh[(size_t)(tb + nt * 16 + fr) * 64 + (mt + 1) * 16 + fq * 4];
            }
#pragma unroll
            for (int j = 0; j < 4; ++j) {
                int a = mt * 16 + fq * 4 + j;
#pragma unroll
                for (int nt = 0; nt < 4; ++nt) {
                    float e = __expf(accS[nt][j] + pbq[mt & 1][nt][j]);
                    lsum[mt][j] += e;
                    Pw[a * 72 + nt * 16 + fr] = f2bf1(e);
                }
            }
        }

        short8 pf[4][2], vf[2][2];
#pragma unroll
        for (int mt = 0; mt < 4; ++mt)
#pragma unroll
            for (int kc = 0; kc < 2; ++kc)
                pf[mt][kc] = *(const short8*)&Pw[(mt * 16 + fr) * 72 + kc * 32 + fq * 8];
#pragma unroll
        for (int ntd = 0; ntd < 2; ++ntd)
#pragma unroll
            for (int kc = 0; kc < 2; ++kc)
                vf[ntd][kc] = *(const short8*)&Vt[(ntd * 16 + fr) * VTP + tb + kc * 32 + fq * 8];

#pragma unroll
        for (int mt = 0; mt < 4; ++mt)
#pragma unroll
            for (int kc = 0; kc < 2; ++kc)
#pragma unroll
                for (int ntd = 0; ntd < 2; ++ntd)
                    accA[mt][ntd] = __builtin_amdgcn_mfma_f32_16x16x32_bf16(pf[mt][kc], vf[ntd][kc], accA[mt][ntd], 0, 0, 0);
    }

#pragma unroll
    for (int mt = 0; mt < 4; ++mt)
#pragma unroll
        for (int j = 0; j < 4; ++j) {
            float s = lsum[mt][j];
            s += __shfl_xor(s, 1);
            s += __shfl_xor(s, 2);
            s += __shfl_xor(s, 4);
            s += __shfl_xor(s, 8);
            lsum[mt][j] = s;
        }
    if (fr == 0) {
#pragma unroll
        for (int mt = 0; mt < 4; ++mt)
#pragma unroll
            for (int j = 0; j < 4; ++j)
                lsum_lds[w][mt * 16 + fq * 4 + j] = lsum[mt][j];
    }

    // TBAA guard: float stores below alias the u16 P reads above (type-punned region)
    asm volatile("s_waitcnt lgkmcnt(0)" ::: "memory");
    __builtin_amdgcn_sched_barrier(0);

#pragma unroll
    for (int mt = 0; mt < 4; ++mt)
#pragma unroll
        for (int ntd = 0; ntd < 2; ++ntd)
#pragma unroll
            for (int j = 0; j < 4; ++j)
                Ow[(mt * 16 + fq * 4 + j) * OSTR + ntd * 16 + fr] = accA[mt][ntd][j];

    __syncthreads();

    // merge 8 waves -> avT. d fastest -> each 32-lane group sweeps 32 banks (conflict-free).
    for (int li = tid; li < 64 * HD; li += 512) {
        int d = li & 31, a = li >> 5;
        float val = 0.f;
        if (a < AGENTS) {
            float L = 0.f, o = 0.f;
#pragma unroll
            for (int ww = 0; ww < 8; ++ww) {
                o += PO[ww][a * OSTR + d];
                L += lsum_lds[ww][a];
            }
            val = o / L;
        }
        avT[d][a] = f2bf1(val);
    }
    __syncthreads();

    // ================= phase 2: q attention + dwc =================
    short8 avf[2][2];
#pragma unroll
    for (int ntd = 0; ntd < 2; ++ntd)
#pragma unroll
        for (int kc = 0; kc < 2; ++kc)
            avf[ntd][kc] = *(const short8*)&avT[ntd * 16 + fr][kc * 32 + fq * 8];

    // preload ALL Q fragments
    short8 qf2[4][2];
#pragma unroll
    for (int hh = 0; hh < 4; ++hh)
#pragma unroll
        for (int mt2 = 0; mt2 < 2; ++mt2)
            qf2[hh][mt2] = *(const short8*)(qkvb + ((size_t)(b * NTOK + w * 128 + hh * 32 + mt2 * 16 + fr)) * QKV_N + h * HD + fq * 8);

    const float* abTh = abT + (size_t)h * AGENTS * NTOK;

#pragma unroll
    for (int hh = 0; hh < 4; ++hh) {
        int hb = w * 128 + hh * 32;
        u16* Pw2 = Pw + (hh & 1) * (32 * 68);   // double buffer: break WAR across hh

        f32x4 abv[2][4];
#pragma unroll
        for (int mt2 = 0; mt2 < 2; ++mt2)
#pragma unroll
            for (int nt = 0; nt < 4; ++nt)
                abv[mt2][nt] = *(const f32x4*)&abTh[(size_t)min(nt * 16 + fr, AGENTS - 1) * NTOK + hb + mt2 * 16 + fq * 4];

        float inv2[2][4];
#pragma unroll
        for (int mt2 = 0; mt2 < 2; ++mt2) {
            f32x4 accS[4];
#pragma unroll
            for (int nt = 0; nt < 4; ++nt)
                accS[nt] = __builtin_amdgcn_mfma_f32_16x16x32_bf16(qf2[hh][mt2], ahf[nt], (f32x4)(0.f), 0, 0, 0);

            float ps[4];
#pragma unroll
            for (int j = 0; j < 4; ++j) ps[j] = 0.f;
#pragma unroll
            for (int j = 0; j < 4; ++j) {
#pragma unroll
                for (int nt = 0; nt < 4; ++nt) {
                    int a = nt * 16 + fr;
                    float s = accS[nt][j] + abv[mt2][nt][j];
                    float ev = (a < AGENTS) ? __expf(s) : 0.f;
                    ps[j] += ev;
                    Pw2[(mt2 * 16 + fq * 4 + j) * 68 + nt * 16 + fr] = f2bf1(ev);
                }
            }
#pragma unroll
            for (int j = 0; j < 4; ++j) {
                ps[j] += __shfl_xor(ps[j], 1);
                ps[j] += __shfl_xor(ps[j], 2);
                ps[j] += __shfl_xor(ps[j], 4);
                ps[j] += __shfl_xor(ps[j], 8);
                inv2[mt2][j] = 1.f / ps[j];
            }
        }

        short8 pf2[2][2];
#pragma unroll
        for (int mt2 = 0; mt2 < 2; ++mt2)
#pragma unroll
            for (int kc = 0; kc < 2; ++kc)
                pf2[mt2][kc] = *(const short8*)&Pw2[(mt2 * 16 + fr) * 68 + kc * 32 + fq * 8];

        f32x4 accO[2][2];
#pragma unroll
        for (int mt2 = 0; mt2 < 2; ++mt2)
#pragma unroll
            for (int ntd = 0; ntd < 2; ++ntd) accO[mt2][ntd] = (f32x4)(0.f);
#pragma unroll
        for (int mt2 = 0; mt2 < 2; ++mt2)
#pragma unroll
            for (int kc = 0; kc < 2; ++kc)
#pragma unroll
                for (int ntd = 0; ntd < 2; ++ntd)
                    accO[mt2][ntd] = __builtin_amdgcn_mfma_f32_16x16x32_bf16(pf2[mt2][kc], avf[ntd][kc], accO[mt2][ntd], 0, 0, 0);

        // fused dwc + bias + bf16 store; normalization applied here (deferred softmax)
        int y = w * 4 + hh;
#pragma unroll
        for (int ntd = 0; ntd < 2; ++ntd) {
            int d = ntd * 16 + fr;
            float wv[9];
#pragma unroll
            for (int t = 0; t < 9; ++t) wv[t] = w9[t][d];
            float bv = bia[d];
            const u16* Vd = &Vt[d * VTP];
#pragma unroll
            for (int mt2 = 0; mt2 < 2; ++mt2) {
                int x0 = mt2 * 16 + fq * 4;
                float sp[3][8];      // tokens x0-2 .. x0+5 per dy row
#pragma unroll
                for (int dy = 0; dy < 3; ++dy) {
                    int yy = y - 1 + dy;
                    if (yy >= 0 && yy < 32) {
                        int base = yy * 32 + x0 - 2;     // even -> 4B-aligned
                        u16x2 r0 = *(const u16x2*)&Vd[base];
                        u16x2 r1 = *(const u16x2*)&Vd[base + 2];
                        u16x2 r2 = *(const u16x2*)&Vd[base + 4];
                        u16x2 r3 = *(const u16x2*)&Vd[base + 6];
                        sp[dy][0] = bf2f(r0[0]); sp[dy][1] = bf2f(r0[1]);
                        sp[dy][2] = bf2f(r1[0]); sp[dy][3] = bf2f(r1[1]);
                        sp[dy][4] = bf2f(r2[0]); sp[dy][5] = bf2f(r2[1]);
                        sp[dy][6] = bf2f(r3[0]); sp[dy][7] = bf2f(r3[1]);
                    } else {
#pragma unroll
                        for (int k = 0; k < 8; ++k) sp[dy][k] = 0.f;
                    }
                }
                float vv[3][6];      // xx = x0-1+k, masked at image edges
#pragma unroll
                for (int dy = 0; dy < 3; ++dy)
#pragma unroll
                    for (int k = 0; k < 6; ++k) {
                        int xx = x0 - 1 + k;
                        vv[dy][k] = (xx >= 0 && xx < 32) ? sp[dy][k + 1] : 0.f;
                    }
#pragma unroll
                for (int j = 0; j < 4; ++j) {
                    float o = accO[mt2][ntd][j] * inv2[mt2][j] + bv;
#pragma unroll
                    for (int dy = 0; dy < 3; ++dy)
#pragma unroll
                        for (int dx = 0; dx < 3; ++dx)
                            o = fmaf(wv[dy * 3 + dx], vv[dy][j + dx], o);
                    int n = y * 32 + x0 + j;
                    outbf[((size_t)(b * 1025 + 1 + n)) * CH + h * HD + d] = f2bf1(o);
                }
            }
        }
    }
}
#undef VTP
#undef OSTR

extern "C" void kernel_launch(void* const* d_in, const int* in_sizes, int n_in,
                              void* d_out, int out_size, void* d_ws, size_t ws_size,
                              hipStream_t stream) {
    const float* x      = (const float*)d_in[0];
    const float* qkv_w  = (const float*)d_in[1];
    const float* proj_w = (const float*)d_in[2];
    const float* proj_b = (const float*)d_in[3];
    const float* dwc_w  = (const float*)d_in[4];
    const float* dwc_b  = (const float*)d_in[5];
    const float* an_b   = (const float*)d_in[6];
    const float* ah_b   = (const float*)d_in[7];
    const float* aw_b   = (const float*)d_in[8];
    const float* na_b   = (const float*)d_in[9];
    const float* ha_b   = (const float*)d_in[10];
    const float* wa_b   = (const float*)d_in[11];
    float* out = (float*)d_out;

    float* ws      = (float*)d_ws;
    u16*   qkvb    = (u16*)ws;                 // 25,165,824 u16 (bf16 qkv)
    float* agents  = ws + 12582912;            // 401,408 f
    float* pbn     = agents + 401408;          // 524,288 f  (n-major [h][n][64])
    float* abT     = pbn + 524288;             // 401,408 f  (a-major [h][a][n])
    u16* xbf  = (u16*)(abT + 401408);          // 8,396,800 u16 (x bf16 -> fused bf16 rows)
    u16* qwbf = xbf + 8396800;                 // 196,608 u16
    u16* pwbf = qwbf + 196608;                 // 65,536 u16

    // conversions (full-x pass pre-writes every xbf line -> fused_attn's partial-line
    // stores hit resident lines instead of RMW write-allocating; R14 lesson)
    f2bf_kernel<<<4100, 256, 0, stream>>>(x, xbf, 8396800 / 8);
    f2bf_w<<<128, 256, 0, stream>>>(qkv_w, proj_w, qwbf, pwbf);
    // 1. qkv(bf16) = xs @ qkv_w^T   (M=32768, N=768, K=256)
    gemm_bf16<<<dim3(256, 6), 256, 0, stream>>>(xbf, qwbf, nullptr, qkvb, 32768, 768, 256, nullptr, 1);
    // 2. agent pooling of q
    pool_kernel<<<BATCH * 7, 256, 0, stream>>>(qkvb, agents);
    // 3. position biases (one launch: pbn n-major + abT a-major)
    bias_kernel<<<HEADS * 64 + (HEADS * AGENTS * NTOK + 255) / 256, 256, 0, stream>>>(
        an_b, ah_b, aw_b, na_b, ha_b, wa_b, pbn, abT);
    // 4. fused agent-attn + q-attn + dwc -> bf16 rows 1..1024 of xbf
    fused_attn<<<BATCH * HEADS, 512, 0, stream>>>(qkvb, agents, pbn, abT, dwc_w, dwc_b, xbf);
    // 5. out = fused @ proj_w^T + proj_b  (M=32800, N=256, K=256)
    gemm_bf16<<<dim3(257, 2), 256, 0, stream>>>(xbf, pwbf, out, nullptr, 32800, 256, 256, proj_b, 0);
}

// Round 18
// 123.867 us; speedup vs baseline: 1.0993x; 1.0129x over previous
//
#include <hip/hip_runtime.h>
#include <hip/hip_bf16.h>

// Problem constants
#define BATCH 32
#define NTOK 1024          // 32x32
#define CH 256
#define HEADS 8
#define HD 32
#define AGENTS 49
#define WIN 32
#define QKV_N 768
#define SCALE 0.17677669529663687f   // 1/sqrt(32)

typedef unsigned short u16;
typedef __attribute__((ext_vector_type(2))) unsigned short u16x2;
typedef __attribute__((ext_vector_type(8))) unsigned short u16x8;
typedef __attribute__((ext_vector_type(8))) short short8;
typedef __attribute__((ext_vector_type(4))) float f32x4;

__device__ __forceinline__ void gload_lds16(const void* g, const void* l) {
    __builtin_amdgcn_global_load_lds(
        (const __attribute__((address_space(1))) unsigned int*)g,
        (__attribute__((address_space(3))) unsigned int*)l, 16, 0, 0);
}

__device__ __forceinline__ u16 f2bf1(float f) {
    unsigned u = __builtin_bit_cast(unsigned, f);
    u += 0x7fffu + ((u >> 16) & 1u);
    return (u16)(u >> 16);
}
__device__ __forceinline__ float bf2f(u16 v) {
    unsigned u = ((unsigned)v) << 16;
    return __builtin_bit_cast(float, u);
}

// ---------------- fp32 -> bf16 conversion, 8 elems/thread ----------------
__global__ void f2bf_kernel(const float* __restrict__ in, u16* __restrict__ out, int n8) {
    int i = blockIdx.x * 256 + threadIdx.x;
    if (i >= n8) return;
    float4 v0 = ((const float4*)in)[i * 2];
    float4 v1 = ((const float4*)in)[i * 2 + 1];
    u16x8 o;
    o[0] = f2bf1(v0.x); o[1] = f2bf1(v0.y); o[2] = f2bf1(v0.z); o[3] = f2bf1(v0.w);
    o[4] = f2bf1(v1.x); o[5] = f2bf1(v1.y); o[6] = f2bf1(v1.z); o[7] = f2bf1(v1.w);
    ((u16x8*)out)[i] = o;
}

// both weight matrices in one launch (blocks 0..95: qkv_w; 96..127: proj_w)
__global__ void f2bf_w(const float* __restrict__ qkv_w, const float* __restrict__ proj_w,
                       u16* __restrict__ qwbf, u16* __restrict__ pwbf) {
    int blk = blockIdx.x;
    const float* in; u16* out; int i;
    if (blk < 96) { in = qkv_w;  out = qwbf; i = blk * 256 + threadIdx.x; }
    else          { in = proj_w; out = pwbf; i = (blk - 96) * 256 + threadIdx.x; }
    float4 v0 = ((const float4*)in)[i * 2];
    float4 v1 = ((const float4*)in)[i * 2 + 1];
    u16x8 o;
    o[0] = f2bf1(v0.x); o[1] = f2bf1(v0.y); o[2] = f2bf1(v0.z); o[3] = f2bf1(v0.w);
    o[4] = f2bf1(v1.x); o[5] = f2bf1(v1.y); o[6] = f2bf1(v1.z); o[7] = f2bf1(v1.w);
    ((u16x8*)out)[i] = o;
}

// ---------------- bf16 MFMA GEMM: C[M,N] = A[M,K] @ B[N,K]^T (+bias) ----------------
__global__ __launch_bounds__(256) void gemm_bf16(const u16* __restrict__ A,
                                                 const u16* __restrict__ B,
                                                 float* __restrict__ C,
                                                 u16* __restrict__ C16,
                                                 int M, int N, int K,
                                                 const float* __restrict__ bias,
                                                 int amode) {
    __shared__ u16 As[128 * 32];
    __shared__ u16 Bs[128 * 32];
    const int tid = threadIdx.x;
    const int lane = tid & 63;
    const int wid = tid >> 6;
    const int row0 = blockIdx.x * 128, col0 = blockIdx.y * 128;
    const int wr = wid >> 1, wc = wid & 1;
    const int fr = lane & 15, fq = lane >> 4;

    f32x4 acc[4][4];
#pragma unroll
    for (int m = 0; m < 4; ++m)
#pragma unroll
        for (int n = 0; n < 4; ++n) acc[m][n] = (f32x4)(0.f);

    for (int k0 = 0; k0 < K; k0 += 32) {
#pragma unroll
        for (int r = 0; r < 2; ++r) {
            int trow = (tid >> 2) + r * 64;
            int tcol = (tid & 3) * 8;
            size_t aoff;
            int grow = row0 + trow;
            if (amode == 1) {
                int bb = grow >> 10, nn = grow & 1023;
                aoff = ((size_t)(bb * 1025 + nn + 1)) * 256 + (size_t)(k0 + tcol);
            } else {
                if (grow >= M) grow = M - 1;
                aoff = (size_t)grow * K + (size_t)(k0 + tcol);
            }
            gload_lds16(A + aoff, (const char*)As + wid * 1024 + r * 4096);
            int brow = col0 + trow;
            gload_lds16(B + (size_t)brow * K + (size_t)(k0 + tcol),
                        (const char*)Bs + wid * 1024 + r * 4096);
        }
        __syncthreads();

        short8 af[4], bf[4];
#pragma unroll
        for (int m = 0; m < 4; ++m)
            af[m] = *(const short8*)&As[(wr * 64 + m * 16 + fr) * 32 + fq * 8];
#pragma unroll
        for (int n = 0; n < 4; ++n)
            bf[n] = *(const short8*)&Bs[(wc * 64 + n * 16 + fr) * 32 + fq * 8];
#pragma unroll
        for (int m = 0; m < 4; ++m)
#pragma unroll
            for (int n = 0; n < 4; ++n)
                acc[m][n] = __builtin_amdgcn_mfma_f32_16x16x32_bf16(af[m], bf[n], acc[m][n], 0, 0, 0);
        __syncthreads();
    }

#pragma unroll
    for (int m = 0; m < 4; ++m) {
#pragma unroll
        for (int j = 0; j < 4; ++j) {
            int row = row0 + wr * 64 + m * 16 + fq * 4 + j;
            if (row < M) {
#pragma unroll
                for (int n = 0; n < 4; ++n) {
                    int col = col0 + wc * 64 + n * 16 + fr;
                    float v = acc[m][n][j];
                    if (bias) v += bias[col];
                    if (C16) C16[(size_t)row * N + col] = f2bf1(v);
                    else     C[(size_t)row * N + col] = v;
                }
            }
        }
    }
}

// ------- adaptive avg pool of q (bf16) -> agents (b,49,256) f32 -------
__global__ __launch_bounds__(256) void pool_kernel(const u16* __restrict__ qkvb,
                                                   float* __restrict__ agents) {
    int b = blockIdx.x / 7, py = blockIdx.x % 7;
    int ch = threadIdx.x;
    int ys = py * 32 / 7, ye = ((py + 1) * 32 + 6) / 7;
    float acc[7];
#pragma unroll
    for (int i = 0; i < 7; ++i) acc[i] = 0.f;
    for (int y = ys; y < ye; ++y) {
        const u16* rowp = qkvb + ((size_t)(b * NTOK + y * 32)) * QKV_N + ch;
#pragma unroll
        for (int PX = 0; PX < 7; ++PX) {
            const int xs = PX * 32 / 7, xe = ((PX + 1) * 32 + 6) / 7;
            float s = 0.f;
            for (int x = xs; x < xe; ++x) s += bf2f(rowp[(size_t)x * QKV_N]);
            acc[PX] += s;
        }
    }
    int rcnt = ye - ys;
#pragma unroll
    for (int PX = 0; PX < 7; ++PX) {
        const int xs = PX * 32 / 7, xe = ((PX + 1) * 32 + 6) / 7;
        agents[((size_t)(b * AGENTS + py * 7 + PX)) * CH + ch] =
            acc[PX] / (float)(rcnt * (xe - xs));
    }
}

// ---------------- bilinear 7x7 sample (half-pixel, clamped) ----------------
__device__ inline float bilin7(const float* __restrict__ m, float sy, float sx) {
    float fy0 = floorf(sy), fx0 = floorf(sx);
    int y0 = (int)fy0, x0 = (int)fx0;
    float fy = sy - fy0, fx = sx - fx0;
    int y0c = min(max(y0, 0), 6), y1c = min(max(y0 + 1, 0), 6);
    int x0c = min(max(x0, 0), 6), x1c = min(max(x0 + 1, 0), 6);
    float v00 = m[y0c * 7 + x0c], v01 = m[y0c * 7 + x1c];
    float v10 = m[y1c * 7 + x0c], v11 = m[y1c * 7 + x1c];
    return (1.f - fy) * ((1.f - fx) * v00 + fx * v01) + fy * ((1.f - fx) * v10 + fx * v11);
}

// merged bias kernel:
// blocks [0, 512):  pbn[h][n][64] (n-major, a rows 49..63 zero)
// blocks [512, 2080): abT[h][a][n] (a-major)
__global__ void bias_kernel(const float* __restrict__ an, const float* __restrict__ ahb,
                            const float* __restrict__ awb, const float* __restrict__ na,
                            const float* __restrict__ hab, const float* __restrict__ wab,
                            float* __restrict__ pbn, float* __restrict__ abT) {
    int blk = blockIdx.x;
    if (blk < HEADS * 64) {
        int h = blk >> 6, a = blk & 63;
        if (a >= AGENTS) {
            for (int n = threadIdx.x; n < NTOK; n += 256)
                pbn[((size_t)(h * NTOK + n)) * 64 + a] = 0.f;
            return;
        }
        const float* m = an + (h * AGENTS + a) * 49;
        for (int n = threadIdx.x; n < NTOK; n += 256) {
            int y = n >> 5, x = n & 31;
            float v = bilin7(m, (y + 0.5f) * (7.f / 32.f) - 0.5f, (x + 0.5f) * (7.f / 32.f) - 0.5f);
            v += ahb[(h * AGENTS + a) * 32 + y] + awb[(h * AGENTS + a) * 32 + x];
            pbn[((size_t)(h * NTOK + n)) * 64 + a] = v;
        }
    } else {
        int idx = (blk - HEADS * 64) * 256 + threadIdx.x;   // = (h*49 + a)*1024 + n
        if (idx >= HEADS * AGENTS * NTOK) return;
        int h = idx / (AGENTS * NTOK);
        int r = idx % (AGENTS * NTOK);
        int a = r / NTOK, n = r % NTOK;
        int y = n >> 5, x = n & 31;
        const float* m = na + (h * AGENTS + a) * 49;
        float v = bilin7(m, (y + 0.5f) * (7.f / 32.f) - 0.5f, (x + 0.5f) * (7.f / 32.f) - 0.5f);
        v += hab[(h * 32 + y) * AGENTS + a] + wab[(h * 32 + x) * AGENTS + a];
        abT[idx] = v;
    }
}

// ============ fused attention: agent-attn (MFMA) + q-attn (MFMA) + dwc ============
// grid = 256 (b,h); 512 threads = 8 waves. Phase 1 = agent attention -> avT in LDS.
// Phase 2 = q attention + depthwise conv; V taps and PV B-operand from the Vt transpose.
// VTP=1038: row stride 519 dw, 519%32=7 -> d-rows land on distinct banks.
// OSTR=36: O-write 2-way (free); merge read d-fastest (conflict-free).
// Phase 2 = R16 form (single P buffer, immediate normalization) — R17's double-buffer +
// deferred normalization measured +1.7us. NO s_setprio (R15: +7us).
#define VTP 1038
#define OSTR 36
__global__ __launch_bounds__(512) void fused_attn(const u16* __restrict__ qkvb,
                                                  const float* __restrict__ agents,
                                                  const float* __restrict__ pbn,
                                                  const float* __restrict__ abT,
                                                  const float* __restrict__ dwc_w,
                                                  const float* __restrict__ dwc_b,
                                                  u16* __restrict__ outbf) {
    int b = blockIdx.x >> 3, h = blockIdx.x & 7;
    int tid = threadIdx.x, lane = tid & 63, w = tid >> 6;
    const int fr = lane & 15, fq = lane >> 4;

    __shared__ u16 ah_lds[64 * 32];       // 4 KB, scale folded, rows 49..63 zero
    __shared__ u16 Vt[32 * VTP];          // 66.4 KB  V^T [dim][token] (both phases)
    __shared__ float PO[8][2304];         // 73.7 KB  per-wave P/O scratch (O: 64 x OSTR=36)
    __shared__ float lsum_lds[8][64];     // 2 KB
    __shared__ u16 avT[32][72];           // 4.6 KB  agent_v^T bf16 (phase 2)
    __shared__ float w9[9][32];           // 1.15 KB
    __shared__ float bia[32];

    u16*   Pw = (u16*)&PO[w][0];
    float* Ow = &PO[w][0];

    // ---- staging (cooperative) ----
    for (int li = tid; li < 64 * 32; li += 512) {
        int a = li >> 5, d = li & 31;
        float v = (a < AGENTS) ? agents[((size_t)(b * AGENTS + a)) * CH + h * HD + d] * SCALE : 0.f;
        ah_lds[li] = f2bf1(v);
    }
    // V^T staging: token-pair repack -> u16x2 writes (<=2-way banked)
    for (int li = tid; li < 512 * 4; li += 512) {
        int p = li >> 2, d8 = (li & 3) * 8;       // tokens 2p,2p+1 ; dims d8..d8+7
        const u16* g0 = &qkvb[((size_t)(b * NTOK + 2 * p)) * QKV_N + 2 * CH + h * HD + d8];
        u16x8 va = *(const u16x8*)g0;
        u16x8 vb = *(const u16x8*)(g0 + QKV_N);
#pragma unroll
        for (int j = 0; j < 8; ++j) {
            u16x2 w2; w2[0] = va[j]; w2[1] = vb[j];
            *(u16x2*)&Vt[(d8 + j) * VTP + 2 * p] = w2;
        }
    }
    for (int li = tid; li < 288; li += 512) {
        int t = li >> 5, d = li & 31;
        w9[t][d] = dwc_w[(h * HD + d) * 9 + t];
    }
    if (tid < 32) bia[tid] = dwc_b[h * HD + tid];
    __syncthreads();

    // ================= phase 1: agent attention =================
    short8 ahf[4];
#pragma unroll
    for (int mt = 0; mt < 4; ++mt)
        ahf[mt] = *(const short8*)&ah_lds[(mt * 16 + fr) * 32 + fq * 8];

    // preload K fragments for BOTH chunks
    short8 kf[2][4];
#pragma unroll
    for (int c2 = 0; c2 < 2; ++c2)
#pragma unroll
        for (int nt = 0; nt < 4; ++nt)
            kf[c2][nt] = *(const short8*)&qkvb[((size_t)(b * NTOK + w * 128 + c2 * 64 + nt * 16 + fr)) * QKV_N + CH + h * HD + fq * 8];

    float lsum[4][4];
#pragma unroll
    for (int mt = 0; mt < 4; ++mt)
#pragma unroll
        for (int j = 0; j < 4; ++j) lsum[mt][j] = 0.f;
    f32x4 accA[4][2];
#pragma unroll
    for (int mt = 0; mt < 4; ++mt)
#pragma unroll
        for (int ntd = 0; ntd < 2; ++ntd) accA[mt][ntd] = (f32x4)(0.f);

    const float* pbnh = pbn + (size_t)h * NTOK * 64;

#pragma unroll
    for (int c2 = 0; c2 < 2; ++c2) {
        int tb = w * 128 + c2 * 64;

        f32x4 pbq[2][4];
#pragma unroll
        for (int nt = 0; nt < 4; ++nt)
            pbq[0][nt] = *(const f32x4*)&pbnh[(size_t)(tb + nt * 16 + fr) * 64 + fq * 4];

#pragma unroll
        for (int mt = 0; mt < 4; ++mt) {
            f32x4 accS[4];
#pragma unroll
            for (int nt = 0; nt < 4; ++nt)
                accS[nt] = __builtin_amdgcn_mfma_f32_16x16x32_bf16(ahf[mt], kf[c2][nt], (f32x4)(0.f), 0, 0, 0);
            if (mt < 3) {
#pragma unroll
                for (int nt = 0; nt < 4; ++nt)
                    pbq[(mt + 1) & 1][nt] = *(const f32x4*)&pbnh[(size_t)(tb + nt * 16 + fr) * 64 + (mt + 1) * 16 + fq * 4];
            }
#pragma unroll
            for (int j = 0; j < 4; ++j) {
                int a = mt * 16 + fq * 4 + j;
#pragma unroll
                for (int nt = 0; nt < 4; ++nt) {
                    float e = __expf(accS[nt][j] + pbq[mt & 1][nt][j]);
                    lsum[mt][j] += e;
                    Pw[a * 72 + nt * 16 + fr] = f2bf1(e);
                }
            }
        }

        short8 pf[4][2], vf[2][2];
#pragma unroll
        for (int mt = 0; mt < 4; ++mt)
#pragma unroll
            for (int kc = 0; kc < 2; ++kc)
                pf[mt][kc] = *(const short8*)&Pw[(mt * 16 + fr) * 72 + kc * 32 + fq * 8];
#pragma unroll
        for (int ntd = 0; ntd < 2; ++ntd)
#pragma unroll
            for (int kc = 0; kc < 2; ++kc)
                vf[ntd][kc] = *(const short8*)&Vt[(ntd * 16 + fr) * VTP + tb + kc * 32 + fq * 8];

#pragma unroll
        for (int mt = 0; mt < 4; ++mt)
#pragma unroll
            for (int kc = 0; kc < 2; ++kc)
#pragma unroll
                for (int ntd = 0; ntd < 2; ++ntd)
                    accA[mt][ntd] = __builtin_amdgcn_mfma_f32_16x16x32_bf16(pf[mt][kc], vf[ntd][kc], accA[mt][ntd], 0, 0, 0);
    }

#pragma unroll
    for (int mt = 0; mt < 4; ++mt)
#pragma unroll
        for (int j = 0; j < 4; ++j) {
            float s = lsum[mt][j];
            s += __shfl_xor(s, 1);
            s += __shfl_xor(s, 2);
            s += __shfl_xor(s, 4);
            s += __shfl_xor(s, 8);
            lsum[mt][j] = s;
        }
    if (fr == 0) {
#pragma unroll
        for (int mt = 0; mt < 4; ++mt)
#pragma unroll
            for (int j = 0; j < 4; ++j)
                lsum_lds[w][mt * 16 + fq * 4 + j] = lsum[mt][j];
    }

    // TBAA guard: float stores below alias the u16 P reads above (type-punned region)
    asm volatile("s_waitcnt lgkmcnt(0)" ::: "memory");
    __builtin_amdgcn_sched_barrier(0);

#pragma unroll
    for (int mt = 0; mt < 4; ++mt)
#pragma unroll
        for (int ntd = 0; ntd < 2; ++ntd)
#pragma unroll
            for (int j = 0; j < 4; ++j)
                Ow[(mt * 16 + fq * 4 + j) * OSTR + ntd * 16 + fr] = accA[mt][ntd][j];

    __syncthreads();

    // merge 8 waves -> avT. d fastest -> each 32-lane group sweeps 32 banks (conflict-free).
    for (int li = tid; li < 64 * HD; li += 512) {
        int d = li & 31, a = li >> 5;
        float val = 0.f;
        if (a < AGENTS) {
            float L = 0.f, o = 0.f;
#pragma unroll
            for (int ww = 0; ww < 8; ++ww) {
                o += PO[ww][a * OSTR + d];
                L += lsum_lds[ww][a];
            }
            val = o / L;
        }
        avT[d][a] = f2bf1(val);
    }
    __syncthreads();

    // ================= phase 2: q attention + dwc =================
    short8 avf[2][2];
#pragma unroll
    for (int ntd = 0; ntd < 2; ++ntd)
#pragma unroll
        for (int kc = 0; kc < 2; ++kc)
            avf[ntd][kc] = *(const short8*)&avT[ntd * 16 + fr][kc * 32 + fq * 8];

    // preload ALL Q fragments
    short8 qf2[4][2];
#pragma unroll
    for (int hh = 0; hh < 4; ++hh)
#pragma unroll
        for (int mt2 = 0; mt2 < 2; ++mt2)
            qf2[hh][mt2] = *(const short8*)(qkvb + ((size_t)(b * NTOK + w * 128 + hh * 32 + mt2 * 16 + fr)) * QKV_N + h * HD + fq * 8);

    const float* abTh = abT + (size_t)h * AGENTS * NTOK;

#pragma unroll
    for (int hh = 0; hh < 4; ++hh) {
        int hb = w * 128 + hh * 32;

        f32x4 abv[2][4];
#pragma unroll
        for (int mt2 = 0; mt2 < 2; ++mt2)
#pragma unroll
            for (int nt = 0; nt < 4; ++nt)
                abv[mt2][nt] = *(const f32x4*)&abTh[(size_t)min(nt * 16 + fr, AGENTS - 1) * NTOK + hb + mt2 * 16 + fq * 4];

#pragma unroll
        for (int mt2 = 0; mt2 < 2; ++mt2) {
            f32x4 accS[4];
#pragma unroll
            for (int nt = 0; nt < 4; ++nt)
                accS[nt] = __builtin_amdgcn_mfma_f32_16x16x32_bf16(qf2[hh][mt2], ahf[nt], (f32x4)(0.f), 0, 0, 0);

            float e[4][4];   // [j][nt]
            float ps[4];
#pragma unroll
            for (int j = 0; j < 4; ++j) ps[j] = 0.f;
#pragma unroll
            for (int j = 0; j < 4; ++j) {
#pragma unroll
                for (int nt = 0; nt < 4; ++nt) {
                    int a = nt * 16 + fr;
                    float s = accS[nt][j] + abv[mt2][nt][j];
                    float ev = (a < AGENTS) ? __expf(s) : 0.f;
                    e[j][nt] = ev;
                    ps[j] += ev;
                }
            }
#pragma unroll
            for (int j = 0; j < 4; ++j) {
                ps[j] += __shfl_xor(ps[j], 1);
                ps[j] += __shfl_xor(ps[j], 2);
                ps[j] += __shfl_xor(ps[j], 4);
                ps[j] += __shfl_xor(ps[j], 8);
            }
#pragma unroll
            for (int j = 0; j < 4; ++j) {
                float inv = 1.f / ps[j];
                int tl = mt2 * 16 + fq * 4 + j;
#pragma unroll
                for (int nt = 0; nt < 4; ++nt)
                    Pw[tl * 68 + nt * 16 + fr] = f2bf1(e[j][nt] * inv);
            }
        }

        short8 pf2[2][2];
#pragma unroll
        for (int mt2 = 0; mt2 < 2; ++mt2)
#pragma unroll
            for (int kc = 0; kc < 2; ++kc)
                pf2[mt2][kc] = *(const short8*)&Pw[(mt2 * 16 + fr) * 68 + kc * 32 + fq * 8];

        f32x4 accO[2][2];
#pragma unroll
        for (int mt2 = 0; mt2 < 2; ++mt2)
#pragma unroll
            for (int ntd = 0; ntd < 2; ++ntd) accO[mt2][ntd] = (f32x4)(0.f);
#pragma unroll
        for (int mt2 = 0; mt2 < 2; ++mt2)
#pragma unroll
            for (int kc = 0; kc < 2; ++kc)
#pragma unroll
                for (int ntd = 0; ntd < 2; ++ntd)
                    accO[mt2][ntd] = __builtin_amdgcn_mfma_f32_16x16x32_bf16(pf2[mt2][kc], avf[ntd][kc], accO[mt2][ntd], 0, 0, 0);

        // fused dwc + bias + bf16 store (C-layout epilogue); V taps via u16x2 spans
        int y = w * 4 + hh;
#pragma unroll
        for (int ntd = 0; ntd < 2; ++ntd) {
            int d = ntd * 16 + fr;
            float wv[9];
#pragma unroll
            for (int t = 0; t < 9; ++t) wv[t] = w9[t][d];
            float bv = bia[d];
            const u16* Vd = &Vt[d * VTP];
#pragma unroll
            for (int mt2 = 0; mt2 < 2; ++mt2) {
                int x0 = mt2 * 16 + fq * 4;
                float sp[3][8];      // tokens x0-2 .. x0+5 per dy row
#pragma unroll
                for (int dy = 0; dy < 3; ++dy) {
                    int yy = y - 1 + dy;
                    if (yy >= 0 && yy < 32) {
                        int base = yy * 32 + x0 - 2;     // even -> 4B-aligned
                        u16x2 r0 = *(const u16x2*)&Vd[base];
                        u16x2 r1 = *(const u16x2*)&Vd[base + 2];
                        u16x2 r2 = *(const u16x2*)&Vd[base + 4];
                        u16x2 r3 = *(const u16x2*)&Vd[base + 6];
                        sp[dy][0] = bf2f(r0[0]); sp[dy][1] = bf2f(r0[1]);
                        sp[dy][2] = bf2f(r1[0]); sp[dy][3] = bf2f(r1[1]);
                        sp[dy][4] = bf2f(r2[0]); sp[dy][5] = bf2f(r2[1]);
                        sp[dy][6] = bf2f(r3[0]); sp[dy][7] = bf2f(r3[1]);
                    } else {
#pragma unroll
                        for (int k = 0; k < 8; ++k) sp[dy][k] = 0.f;
                    }
                }
                float vv[3][6];      // xx = x0-1+k, masked at image edges
#pragma unroll
                for (int dy = 0; dy < 3; ++dy)
#pragma unroll
                    for (int k = 0; k < 6; ++k) {
                        int xx = x0 - 1 + k;
                        vv[dy][k] = (xx >= 0 && xx < 32) ? sp[dy][k + 1] : 0.f;
                    }
#pragma unroll
                for (int j = 0; j < 4; ++j) {
                    float o = accO[mt2][ntd][j] + bv;
#pragma unroll
                    for (int dy = 0; dy < 3; ++dy)
#pragma unroll
                        for (int dx = 0; dx < 3; ++dx)
                            o = fmaf(wv[dy * 3 + dx], vv[dy][j + dx], o);
                    int n = y * 32 + x0 + j;
                    outbf[((size_t)(b * 1025 + 1 + n)) * CH + h * HD + d] = f2bf1(o);
                }
            }
        }
    }
}
#undef VTP
#undef OSTR

extern "C" void kernel_launch(void* const* d_in, const int* in_sizes, int n_in,
                              void* d_out, int out_size, void* d_ws, size_t ws_size,
                              hipStream_t stream) {
    const float* x      = (const float*)d_in[0];
    const float* qkv_w  = (const float*)d_in[1];
    const float* proj_w = (const float*)d_in[2];
    const float* proj_b = (const float*)d_in[3];
    const float* dwc_w  = (const float*)d_in[4];
    const float* dwc_b  = (const float*)d_in[5];
    const float* an_b   = (const float*)d_in[6];
    const float* ah_b   = (const float*)d_in[7];
    const float* aw_b   = (const float*)d_in[8];
    const float* na_b   = (const float*)d_in[9];
    const float* ha_b   = (const float*)d_in[10];
    const float* wa_b   = (const float*)d_in[11];
    float* out = (float*)d_out;

    float* ws      = (float*)d_ws;
    u16*   qkvb    = (u16*)ws;                 // 25,165,824 u16 (bf16 qkv)
    float* agents  = ws + 12582912;            // 401,408 f
    float* pbn     = agents + 401408;          // 524,288 f  (n-major [h][n][64])
    float* abT     = pbn + 524288;             // 401,408 f  (a-major [h][a][n])
    u16* xbf  = (u16*)(abT + 401408);          // 8,396,800 u16 (x bf16 -> fused bf16 rows)
    u16* qwbf = xbf + 8396800;                 // 196,608 u16
    u16* pwbf = qwbf + 196608;                 // 65,536 u16

    // conversions (full-x pass pre-writes every xbf line -> fused_attn's partial-line
    // stores hit resident lines instead of RMW write-allocating; R14 lesson)
    f2bf_kernel<<<4100, 256, 0, stream>>>(x, xbf, 8396800 / 8);
    f2bf_w<<<128, 256, 0, stream>>>(qkv_w, proj_w, qwbf, pwbf);
    // 1. qkv(bf16) = xs @ qkv_w^T   (M=32768, N=768, K=256)
    gemm_bf16<<<dim3(256, 6), 256, 0, stream>>>(xbf, qwbf, nullptr, qkvb, 32768, 768, 256, nullptr, 1);
    // 2. agent pooling of q
    pool_kernel<<<BATCH * 7, 256, 0, stream>>>(qkvb, agents);
    // 3. position biases (one launch: pbn n-major + abT a-major)
    bias_kernel<<<HEADS * 64 + (HEADS * AGENTS * NTOK + 255) / 256, 256, 0, stream>>>(
        an_b, ah_b, aw_b, na_b, ha_b, wa_b, pbn, abT);
    // 4. fused agent-attn + q-attn + dwc -> bf16 rows 1..1024 of xbf
    fused_attn<<<BATCH * HEADS, 512, 0, stream>>>(qkvb, agents, pbn, abT, dwc_w, dwc_b, xbf);
    // 5. out = fused @ proj_w^T + proj_b  (M=32800, N=256, K=256)
    gemm_bf16<<<dim3(257, 2), 256, 0, stream>>>(xbf, pwbf, out, nullptr, 32800, 256, 256, proj_b, 0);
}